// Round 9
// baseline (164.426 us; speedup 1.0000x reference)
//
#include <hip/hip_runtime.h>
#include <stdint.h>

#define EPS_BN 1e-5f

typedef __attribute__((ext_vector_type(8))) short short8;
typedef __attribute__((ext_vector_type(4))) float floatx4;

__device__ __forceinline__ unsigned short f2bf(float f) {
    unsigned u = __builtin_bit_cast(unsigned, f);
    u += 0x7fffu + ((u >> 16) & 1u);   // RNE
    return (unsigned short)(u >> 16);
}
__device__ __forceinline__ float bf2f(unsigned short h) {
    unsigned u = ((unsigned)h) << 16;
    return __builtin_bit_cast(float, u);
}
__device__ __forceinline__ void unpack8(uint4 q, float* v) {
    v[0] = bf2f((unsigned short)q.x); v[1] = bf2f((unsigned short)(q.x >> 16));
    v[2] = bf2f((unsigned short)q.y); v[3] = bf2f((unsigned short)(q.y >> 16));
    v[4] = bf2f((unsigned short)q.z); v[5] = bf2f((unsigned short)(q.z >> 16));
    v[6] = bf2f((unsigned short)q.w); v[7] = bf2f((unsigned short)(q.w >> 16));
}
__device__ __forceinline__ uint4 pack8(const float* v) {
    uint4 q;
    q.x = (unsigned)f2bf(v[0]) | ((unsigned)f2bf(v[1]) << 16);
    q.y = (unsigned)f2bf(v[2]) | ((unsigned)f2bf(v[3]) << 16);
    q.z = (unsigned)f2bf(v[4]) | ((unsigned)f2bf(v[5]) << 16);
    q.w = (unsigned)f2bf(v[6]) | ((unsigned)f2bf(v[7]) << 16);
    return q;
}

__device__ __forceinline__ void async_copy16(const unsigned short* g, unsigned short* l) {
    __builtin_amdgcn_global_load_lds(
        (const __attribute__((address_space(1))) unsigned int*)(const void*)g,
        (__attribute__((address_space(3))) unsigned int*)(void*)l,
        16, 0, 0);
}

// scale = g*rsqrt(var+eps), shift = b - mean*scale, from raw sum/sumsq
__device__ __forceinline__ void bn_coef(const float* st, int n, int c, float invN,
                                        const float* gg, const float* bb,
                                        float* scl, float* shf) {
    const float mean = st[c] * invN;
    const float var = st[n + c] * invN - mean * mean;
    const float sc = gg[c & 15] * rsqrtf(var + EPS_BN);
    scl[c] = sc;
    shf[c] = bb[c & 15] - mean * sc;
}

// =====================================================================
// pack: fp32 NCHW -> padded (halo-zeroed) bf16 NHWC, ch-half swizzled by
// (paddedcol>>2)&1. Blocks >= 6303 do weight fragments + stats zero.
// =====================================================================
__global__ __launch_bounds__(256)
void pack_kernel(const float* __restrict__ support, const float* __restrict__ anchor,
                 unsigned short* __restrict__ spad, unsigned short* __restrict__ apad,
                 const float* __restrict__ rw, const float* __restrict__ cw,
                 const float* __restrict__ jw, unsigned short* __restrict__ frag,
                 float* __restrict__ stats)
{
    const int tid = threadIdx.x;
    if (blockIdx.x >= 6303) {
        const int bx = blockIdx.x - 6303;
        if (bx == 4) {
            #pragma unroll
            for (int k = 0; k < 3; ++k) stats[k * 256 + tid] = 0.f;
            return;
        }
        const int idx = bx * 256 + tid;
        if (idx >= 960) return;
        const int combo = idx >> 6, lane = idx & 63;
        const int cv = combo / 5, j = combo - cv * 5;
        const float* w = (cv == 0) ? rw : (cv == 1) ? cw : jw;
        const int o = lane & 15, g = lane >> 4;
        unsigned short e8[8];
        #pragma unroll
        for (int e = 0; e < 8; ++e) {
            const int k = j * 32 + g * 8 + e;
            unsigned short val = 0;
            if (k < 144) {
                const int t = k >> 4, i = k & 15;
                const int kh = t / 3, kw = t - kh * 3;
                val = f2bf(w[((o * 16 + i) * 3 + kh) * 3 + kw]);
            }
            e8[e] = val;
        }
        *(uint4*)(frag + ((size_t)combo * 64 + lane) * 8) =
            make_uint4((unsigned)e8[0] | ((unsigned)e8[1] << 16), (unsigned)e8[2] | ((unsigned)e8[3] << 16),
                       (unsigned)e8[4] | ((unsigned)e8[5] << 16), (unsigned)e8[6] | ((unsigned)e8[7] << 16));
        return;
    }
    const int idx = blockIdx.x * 256 + tid;
    if (idx >= 168 * 9604) return;
    const int img = idx / 9604;
    const int rem = idx - img * 9604;
    const int pr = rem / 98, pc = rem - pr * 98;
    const int gh = pr - 1, gw = pc - 1;
    const bool ok = (gh >= 0) & (gh < 96) & (gw >= 0) & (gw < 96);
    const float* src = (img < 160) ? (support + (size_t)img * 147456)
                                   : (anchor + (size_t)(img - 160) * 147456);
    unsigned short* dst = (img < 160) ? (spad + (size_t)img * 9604 * 16)
                                      : (apad + (size_t)(img - 160) * 9604 * 16);
    const int gbase = gh * 96 + gw;
    unsigned pk[8];
    #pragma unroll
    for (int c = 0; c < 8; ++c) {
        const float v0 = ok ? src[(2 * c) * 9216 + gbase] : 0.f;
        const float v1 = ok ? src[(2 * c + 1) * 9216 + gbase] : 0.f;
        pk[c] = (unsigned)f2bf(v0) | ((unsigned)f2bf(v1) << 16);
    }
    const int sw = (pc >> 2) & 1;
    unsigned short* p = dst + (size_t)rem * 16;
    *(uint4*)(p + (sw << 3)) = make_uint4(pk[0], pk[1], pk[2], pk[3]);       // ch 0..7
    *(uint4*)(p + ((sw ^ 1) << 3)) = make_uint4(pk[4], pk[5], pk[6], pk[7]); // ch 8..15
}

// =====================================================================
// conv 3x3 pad1 via MFMA (A=weights 16o x k, B=pixels k x 16pix).
// POOLA templated (2x2 maxpool pre-BN on A output), `two` runtime.
// =====================================================================
template<bool POOLA>
__device__ __forceinline__ void conv_tile(
    unsigned short* lds, float* red,
    const unsigned short* __restrict__ imgin,
    const unsigned short* __restrict__ fragA, const float* __restrict__ bA,
    const unsigned short* __restrict__ fragB, const float* __restrict__ bB,
    unsigned short* __restrict__ outAimg, unsigned short* __restrict__ outBimg,
    float* __restrict__ statsA, float* __restrict__ statsB,
    const int r0b, const bool two)
{
    const int tid = threadIdx.x;
    const int lane = tid & 63;
    const int wv = tid >> 6;

    const unsigned short* gsrc = imgin + (size_t)(r0b * 8 * 98) * 16;
    #pragma unroll
    for (int k = 0; k < 8; ++k) {
        const int chunk = k * 256 + tid;
        if (chunk < 1960)
            async_copy16(gsrc + (size_t)chunk * 8, lds + (k * 256 + wv * 64) * 8);
    }

    const int n = lane & 15, g = lane >> 4;
    short8 fA[5], fB[5];
    #pragma unroll
    for (int j = 0; j < 5; ++j) {
        fA[j] = *(const short8*)(fragA + ((size_t)j * 64 + lane) * 8);
        if (two) fB[j] = *(const short8*)(fragB + ((size_t)j * 64 + lane) * 8);
    }
    const float4 bA4 = *(const float4*)(bA + 4 * g);
    float4 bB4 = make_float4(0.f, 0.f, 0.f, 0.f);
    if (two) bB4 = *(const float4*)(bB + 4 * g);
    const float biasA[4] = {bA4.x, bA4.y, bA4.z, bA4.w};
    const float biasB[4] = {bB4.x, bB4.y, bB4.z, bB4.w};

    __syncthreads();

    float s1A[4] = {0.f, 0.f, 0.f, 0.f}, s2A[4] = {0.f, 0.f, 0.f, 0.f};
    float s1B[4] = {0.f, 0.f, 0.f, 0.f}, s2B[4] = {0.f, 0.f, 0.f, 0.f};

    for (int cg = 0; cg < 6; ++cg) {
        float pA[2][4], pB[2][4];
        #pragma unroll
        for (int tr = 0; tr < 2; ++tr) {
            const int lr = 2 * wv + tr;
            floatx4 aA = {0.f, 0.f, 0.f, 0.f};
            floatx4 aB = {0.f, 0.f, 0.f, 0.f};
            #pragma unroll
            for (int j = 0; j < 5; ++j) {
                const int t = (j < 4) ? (2 * j + (g >> 1)) : 8;
                const int kh = t / 3, kw = t - kh * 3;
                const int ldscol = cg * 16 + n + kw;
                const int half = (g & 1) ^ ((ldscol >> 2) & 1);
                const short8 a = *(const short8*)&lds[((lr + kh) * 98 + ldscol) * 16 + (half << 3)];
                aA = __builtin_amdgcn_mfma_f32_16x16x32_bf16(fA[j], a, aA, 0, 0, 0);
                if (two) aB = __builtin_amdgcn_mfma_f32_16x16x32_bf16(fB[j], a, aB, 0, 0, 0);
            }
            #pragma unroll
            for (int r = 0; r < 4; ++r) {
                const float vA = aA[r] + biasA[r];
                pA[tr][r] = vA; s1A[r] += vA; s2A[r] += vA * vA;
                if (two) {
                    const float vB = aB[r] + biasB[r];
                    pB[tr][r] = vB; s1B[r] += vB; s2B[r] += vB * vB;
                }
            }
            const int grow = r0b * 8 + lr;
            const size_t pixbase = ((size_t)(grow * 96 + cg * 16 + n)) * 16 + 4 * g;
            if (two)
                *(uint2*)(outBimg + pixbase) =
                    make_uint2((unsigned)f2bf(pB[tr][0]) | ((unsigned)f2bf(pB[tr][1]) << 16),
                               (unsigned)f2bf(pB[tr][2]) | ((unsigned)f2bf(pB[tr][3]) << 16));
            if (!POOLA)
                *(uint2*)(outAimg + pixbase) =
                    make_uint2((unsigned)f2bf(pA[tr][0]) | ((unsigned)f2bf(pA[tr][1]) << 16),
                               (unsigned)f2bf(pA[tr][2]) | ((unsigned)f2bf(pA[tr][3]) << 16));
        }
        if (POOLA) {
            float pm[4];
            #pragma unroll
            for (int r = 0; r < 4; ++r) {
                pm[r] = fmaxf(pA[0][r], pA[1][r]);
                pm[r] = fmaxf(pm[r], __shfl_xor(pm[r], 1));
            }
            if (!(n & 1)) {
                const int orow = r0b * 4 + wv;
                const size_t ob = ((size_t)(orow * 48 + cg * 8 + (n >> 1))) * 16 + 4 * g;
                *(uint2*)(outAimg + ob) =
                    make_uint2((unsigned)f2bf(pm[0]) | ((unsigned)f2bf(pm[1]) << 16),
                               (unsigned)f2bf(pm[2]) | ((unsigned)f2bf(pm[3]) << 16));
            }
        }
    }

    #pragma unroll
    for (int r = 0; r < 4; ++r) {
        #pragma unroll
        for (int d = 1; d < 16; d <<= 1) {
            s1A[r] += __shfl_xor(s1A[r], d); s2A[r] += __shfl_xor(s2A[r], d);
            if (two) { s1B[r] += __shfl_xor(s1B[r], d); s2B[r] += __shfl_xor(s2B[r], d); }
        }
    }
    if (n == 0) {
        #pragma unroll
        for (int r = 0; r < 4; ++r) {
            red[(wv * 4 + 0) * 16 + g * 4 + r] = s1A[r];
            red[(wv * 4 + 1) * 16 + g * 4 + r] = s2A[r];
            if (two) {
                red[(wv * 4 + 2) * 16 + g * 4 + r] = s1B[r];
                red[(wv * 4 + 3) * 16 + g * 4 + r] = s2B[r];
            }
        }
    }
    __syncthreads();
    if (tid < (two ? 64 : 32)) {
        const int st = tid >> 4, oc = tid & 15;
        const float v = red[(0 * 4 + st) * 16 + oc] + red[(1 * 4 + st) * 16 + oc] +
                        red[(2 * 4 + st) * 16 + oc] + red[(3 * 4 + st) * 16 + oc];
        float* dst = (st < 2) ? statsA : statsB;
        atomicAdd(&dst[(st & 1) * 16 + oc], v);
    }
}

// main conv: blocks [0,1920) = support (dual conv), [1920,2016) = anchor
__global__ __launch_bounds__(256)
void conv_main_kernel(const unsigned short* __restrict__ spad, const unsigned short* __restrict__ apad,
                      const unsigned short* __restrict__ fragR, const float* __restrict__ rb,
                      const unsigned short* __restrict__ fragC, const float* __restrict__ cb,
                      unsigned short* __restrict__ srp, unsigned short* __restrict__ sxpe,
                      unsigned short* __restrict__ axp,
                      float* __restrict__ statsSr, float* __restrict__ statsSx,
                      float* __restrict__ statsAx)
{
    __shared__ __align__(16) unsigned short lds[10 * 98 * 16];
    __shared__ float red[4 * 4 * 16];
    const bool two = blockIdx.x < 1920;
    const int bid = two ? blockIdx.x : blockIdx.x - 1920;
    const int img = bid / 12;
    const int r0b = bid - img * 12;
    const unsigned short* in = (two ? spad : apad) + (size_t)img * 9604 * 16;
    unsigned short* outA = (two ? srp : axp) + (size_t)img * 2304 * 16;
    unsigned short* outB = sxpe + (size_t)img * 9216 * 16;
    conv_tile<true>(lds, red, in, fragR, rb, fragC, cb, outA, outB,
                    two ? statsSr : statsAx, statsSx, r0b, two);
}

// projector conv (deep -> pre_j, unpooled)
__global__ __launch_bounds__(256)
void conv_j_kernel(const unsigned short* __restrict__ deeppad,
                   const unsigned short* __restrict__ fragJ, const float* __restrict__ jb,
                   unsigned short* __restrict__ pre_j, float* __restrict__ statsJ)
{
    __shared__ __align__(16) unsigned short lds[10 * 98 * 16];
    __shared__ float red[4 * 4 * 16];
    const int img = blockIdx.x / 12;
    const int r0b = blockIdx.x - img * 12;
    conv_tile<false>(lds, red, deeppad + (size_t)img * 9604 * 16, fragJ, jb, nullptr, nullptr,
                     pre_j + (size_t)img * 9216 * 16, nullptr, statsJ, nullptr, r0b, false);
}

// =====================================================================
// FUSED pe v2: block owns 64 pixels x all 20 s. LDS holds ONLY the
// channel-sum psum (8.7 KB) -> high occupancy. Pass 1 streams sx once,
// accumulating psum. Pass 2 re-reads sx from global (L2-hot: same 40KB
// the block just touched) for loo, does the MFMA 1x1 conv in place, and
// accumulates per-(s,c) stats via 8-shfl fold-tree + atomicAdd.
// In-place safe: each wave reads sx[s][pix] strictly before writing
// pe[s][pix]; planes are disjoint across waves.
// Blocks 0..12 also zero the deeppad halo ring.
// =====================================================================
__global__ __launch_bounds__(256)
void pe_fused_kernel(const unsigned short* __restrict__ spad, unsigned short* __restrict__ sxpe,
                     const float* __restrict__ statsSx,
                     const float* __restrict__ cgm, const float* __restrict__ cbt,
                     const float* __restrict__ pw, const float* __restrict__ pb,
                     float* __restrict__ statsPe, unsigned short* __restrict__ deeppad)
{
    __shared__ float psum[2][64][17];
    __shared__ float sscl[16], sshf[16];

    const int tid = threadIdx.x;
    if (blockIdx.x < 13) {   // deeppad halo zero (b=0 chunks)
        const int idx = blockIdx.x * 256 + tid;
        if (idx < 8 * 388) {
            const int img = idx / 388;
            const int h = idx - img * 388;
            int pr, pc;
            if (h < 98)       { pr = 0;           pc = h; }
            else if (h < 196) { pr = 97;          pc = h - 98; }
            else if (h < 292) { pr = h - 196 + 1; pc = 0; }
            else              { pr = h - 292 + 1; pc = 97; }
            unsigned short* p = deeppad + ((size_t)img * 9604 + pr * 98 + pc) * 16;
            *(uint4*)p = make_uint4(0, 0, 0, 0);
            *(uint4*)(p + 8) = make_uint4(0, 0, 0, 0);
        }
    }
    if (tid < 16) bn_coef(statsSx, 16, tid, 1.f / 1474560.f, cgm, cbt, sscl, sshf);
    const int b = blockIdx.x / 144;
    const int chunk = blockIdx.x - b * 144;
    const int pix0 = chunk * 64;
    __syncthreads();

    // ---- pass 1: thread = (pixel px, s-group of 5); psum only ----
    const int px = tid & 63;
    const int sgrp = tid >> 6;              // 0..3
    float acc[16];
    #pragma unroll
    for (int c = 0; c < 16; ++c) acc[c] = 0.f;
    {
        const unsigned short* srcp = sxpe + ((size_t)(b * 20 + sgrp * 5) * 9216 + pix0 + px) * 16;
        for (int s = 0; s < 5; ++s) {
            float v[16];
            unpack8(*(const uint4*)srcp, v);
            unpack8(*(const uint4*)(srcp + 8), v + 8);
            #pragma unroll
            for (int c = 0; c < 16; ++c) acc[c] += fmaxf(v[c] * sscl[c] + sshf[c], 0.f);
            srcp += (size_t)9216 * 16;
        }
    }
    if (sgrp < 2) {
        #pragma unroll
        for (int c = 0; c < 16; ++c) psum[sgrp][px][c] = acc[c];
    }
    __syncthreads();
    if (sgrp >= 2) {
        #pragma unroll
        for (int c = 0; c < 16; ++c) psum[sgrp - 2][px][c] += acc[c];
    }
    __syncthreads();
    {
        const int cq = tid >> 6, px2 = tid & 63;
        #pragma unroll
        for (int i = 0; i < 4; ++i) psum[0][px2][cq * 4 + i] += psum[1][px2][cq * 4 + i];
    }
    __syncthreads();

    // ---- pass 2: wave wv owns s in {wv, wv+4, ..., wv+16} ----
    const int lane = tid & 63, wv = tid >> 6;
    const int p = lane & 15, g = lane >> 4;
    const int c0 = (g & 1) * 8;
    short8 fw;
    {
        const float4 wa = *(const float4*)(pw + p * 32 + g * 8);
        const float4 wb = *(const float4*)(pw + p * 32 + g * 8 + 4);
        fw[0] = (short)f2bf(wa.x); fw[1] = (short)f2bf(wa.y);
        fw[2] = (short)f2bf(wa.z); fw[3] = (short)f2bf(wa.w);
        fw[4] = (short)f2bf(wb.x); fw[5] = (short)f2bf(wb.y);
        fw[6] = (short)f2bf(wb.z); fw[7] = (short)f2bf(wb.w);
    }
    const float4 b4 = *(const float4*)(pb + 4 * g);
    const float bias[4] = {b4.x, b4.y, b4.z, b4.w};

    for (int sw = 0; sw < 5; ++sw) {
        const int s = wv + sw * 4;
        const int img = b * 20 + s;
        const unsigned short* imgspad = spad + (size_t)img * 9604 * 16;
        unsigned short* imgsx = sxpe + ((size_t)img * 9216 + pix0) * 16;
        float s1[4] = {0.f, 0.f, 0.f, 0.f}, s2[4] = {0.f, 0.f, 0.f, 0.f};
        for (int tile = 0; tile < 4; ++tile) {
            const int pixl = tile * 16 + p;
            short8 bf;
            if (g < 2) {
                const int pix = pix0 + pixl;
                const int row = pix / 96, col = pix - row * 96;
                const int sw2 = ((col + 1) >> 2) & 1;
                bf = *(const short8*)(imgspad + ((row + 1) * 98 + col + 1) * 16 + (((g ^ sw2) & 1) << 3));
            } else {
                float xv[8];
                unpack8(*(const uint4*)(imgsx + (size_t)pixl * 16 + c0), xv);
                #pragma unroll
                for (int e = 0; e < 8; ++e) {
                    const float relu = fmaxf(xv[e] * sscl[c0 + e] + sshf[c0 + e], 0.f);
                    bf[e] = (short)f2bf(psum[0][pixl][c0 + e] - relu);
                }
            }
            floatx4 acc2 = {0.f, 0.f, 0.f, 0.f};
            acc2 = __builtin_amdgcn_mfma_f32_16x16x32_bf16(fw, bf, acc2, 0, 0, 0);
            const float v0 = acc2[0] + bias[0], v1 = acc2[1] + bias[1];
            const float v2 = acc2[2] + bias[2], v3 = acc2[3] + bias[3];
            s1[0] += v0; s1[1] += v1; s1[2] += v2; s1[3] += v3;
            s2[0] += v0 * v0; s2[1] += v1 * v1; s2[2] += v2 * v2; s2[3] += v3 * v3;
            *(uint2*)(imgsx + (size_t)pixl * 16 + 4 * g) =
                make_uint2((unsigned)f2bf(v0) | ((unsigned)f2bf(v1) << 16),
                           (unsigned)f2bf(v2) | ((unsigned)f2bf(v3) << 16));
        }
        // 8-shfl fold-tree over the 16 p-lanes: v8 = {s1[0..3], s2[0..3]}
        float v8[8] = {s1[0], s1[1], s1[2], s1[3], s2[0], s2[1], s2[2], s2[3]};
        {   // d=1: stat bit
            const bool hi = (lane & 1) != 0;
            float t[4], u[4];
            #pragma unroll
            for (int k = 0; k < 4; ++k) { t[k] = hi ? v8[k + 4] : v8[k]; u[k] = hi ? v8[k] : v8[k + 4]; }
            #pragma unroll
            for (int k = 0; k < 4; ++k) v8[k] = t[k] + __shfl_xor(u[k], 1);
        }
        {   // d=2: r bit1
            const bool hi = (lane & 2) != 0;
            float t[2], u[2];
            #pragma unroll
            for (int k = 0; k < 2; ++k) { t[k] = hi ? v8[k + 2] : v8[k]; u[k] = hi ? v8[k] : v8[k + 2]; }
            #pragma unroll
            for (int k = 0; k < 2; ++k) v8[k] = t[k] + __shfl_xor(u[k], 2);
        }
        {   // d=4: r bit0
            const bool hi = (lane & 4) != 0;
            const float t = hi ? v8[1] : v8[0], u = hi ? v8[0] : v8[1];
            v8[0] = t + __shfl_xor(u, 4);
        }
        v8[0] += __shfl_xor(v8[0], 8);
        if (p < 8) {
            const int stat = p & 1;
            const int r = ((p >> 1) & 1) * 2 + ((p >> 2) & 1);
            atomicAdd(&statsPe[stat * 320 + s * 16 + g * 4 + r], v8[0]);
        }
    }
}

// ---------------- deep: mean_s relu(bn_{s,c}(pe)), 4-way s split, coef prologue
__global__ __launch_bounds__(256)
void deep_kernel(const unsigned short* __restrict__ pe, const float* __restrict__ statsPe,
                 const float* __restrict__ pg, const float* __restrict__ pbt,
                 unsigned short* __restrict__ deeppad)
{
    __shared__ float scl[320], shf[320];
    __shared__ float part[3][64][17];
    const int tid = threadIdx.x;
    for (int i = tid; i < 320; i += 256)
        bn_coef(statsPe, 320, i, 1.f / 73728.f, pg, pbt, scl, shf);
    const int b = blockIdx.x / 144;
    const int chunk = blockIdx.x - b * 144;
    const int px = tid & 63, sg = tid >> 6;
    const int pix = chunk * 64 + px;
    __syncthreads();
    float acc[16];
    #pragma unroll
    for (int c = 0; c < 16; ++c) acc[c] = 0.f;
    const unsigned short* p = pe + ((size_t)(b * 20 + sg * 5) * 9216 + pix) * 16;
    #pragma unroll
    for (int s = 0; s < 5; ++s) {
        const int si = sg * 5 + s;
        float v[16];
        unpack8(*(const uint4*)p, v);
        unpack8(*(const uint4*)(p + 8), v + 8);
        #pragma unroll
        for (int c = 0; c < 16; ++c) acc[c] += fmaxf(v[c] * scl[si * 16 + c] + shf[si * 16 + c], 0.f);
        p += 9216 * 16;
    }
    if (sg > 0) {
        #pragma unroll
        for (int c = 0; c < 16; ++c) part[sg - 1][px][c] = acc[c];
    }
    __syncthreads();
    if (sg == 0) {
        #pragma unroll
        for (int c = 0; c < 16; ++c)
            acc[c] = (acc[c] + part[0][px][c] + part[1][px][c] + part[2][px][c]) * 0.05f;
        const int row = pix / 96, col = pix - row * 96;
        const int sw = ((col + 1) >> 2) & 1;
        unsigned short* d = deeppad + ((size_t)b * 9604 + (row + 1) * 98 + col + 1) * 16;
        *(uint4*)(d + (sw << 3)) = pack8(acc);
        *(uint4*)(d + ((sw ^ 1) << 3)) = pack8(acc + 8);
    }
}

// ---------------- proj = maxpool2(softmax_ch(bn(conv_j))), coef prologue
__global__ __launch_bounds__(256)
void proj_kernel(const unsigned short* __restrict__ pj, const float* __restrict__ statsJ,
                 const float* __restrict__ jg, const float* __restrict__ jbt,
                 float* __restrict__ proj)
{
    __shared__ float scl[16], shf[16];
    const int tid = threadIdx.x;
    if (tid < 16) bn_coef(statsJ, 16, tid, 1.f / 73728.f, jg, jbt, scl, shf);
    const int b = blockIdx.x / 9;
    const int opix = (blockIdx.x - b * 9) * 256 + tid;
    __syncthreads();
    const int oi = opix / 48, oj = opix - oi * 48;
    float mx[16];
    #pragma unroll
    for (int c = 0; c < 16; ++c) mx[c] = 0.f;
    #pragma unroll
    for (int dy = 0; dy < 2; ++dy) {
        const unsigned short* q = pj + ((size_t)b * 9216 + (2 * oi + dy) * 96 + 2 * oj) * 16;
        #pragma unroll
        for (int dx = 0; dx < 2; ++dx) {
            float v[16]; float mval = -1e30f;
            unpack8(*(const uint4*)(q + dx * 16), v);
            unpack8(*(const uint4*)(q + dx * 16 + 8), v + 8);
            #pragma unroll
            for (int c = 0; c < 16; ++c) { v[c] = v[c] * scl[c] + shf[c]; mval = fmaxf(mval, v[c]); }
            float ssum = 0.f;
            #pragma unroll
            for (int c = 0; c < 16; ++c) { v[c] = __expf(v[c] - mval); ssum += v[c]; }
            const float inv = 1.f / ssum;
            #pragma unroll
            for (int c = 0; c < 16; ++c) mx[c] = fmaxf(mx[c], v[c] * inv);
        }
    }
    float* o = proj + ((size_t)b * 2304 + opix) * 16;
    #pragma unroll
    for (int q2 = 0; q2 < 4; ++q2)
        *(float4*)(o + 4 * q2) = make_float4(mx[4 * q2], mx[4 * q2 + 1], mx[4 * q2 + 2], mx[4 * q2 + 3]);
}

// ---------------- merged outputs: blocks [0,1440) support, [1440,1512) anchor
__global__ __launch_bounds__(256)
void out_kernel(const unsigned short* __restrict__ srp, const unsigned short* __restrict__ axp,
                const float* __restrict__ statsSr, const float* __restrict__ statsAx,
                const float* __restrict__ rg, const float* __restrict__ rbt,
                const float* __restrict__ proj, float* __restrict__ outS,
                float* __restrict__ outA)
{
    __shared__ float scl[16], shf[16];
    const int tid = threadIdx.x;
    const bool sup = blockIdx.x < 1440;
    if (tid < 16) {
        if (sup) bn_coef(statsSr, 16, tid, 1.f / 1474560.f, rg, rbt, scl, shf);
        else     bn_coef(statsAx, 16, tid, 1.f / 73728.f, rg, rbt, scl, shf);
    }
    const int bid = sup ? blockIdx.x : blockIdx.x - 1440;
    const int bs = bid / 9;
    const int opix = (bid - bs * 9) * 256 + tid;
    const int b = sup ? bs / 20 : bs;
    __syncthreads();
    const unsigned short* p = (sup ? srp : axp) + ((size_t)bs * 2304 + opix) * 16;
    float v[16];
    unpack8(*(const uint4*)p, v);
    unpack8(*(const uint4*)(p + 8), v + 8);
    const float* pr = proj + ((size_t)b * 2304 + opix) * 16;
    float* o = sup ? outS : outA;
    #pragma unroll
    for (int c = 0; c < 16; ++c)
        o[((size_t)bs * 16 + c) * 2304 + opix] = fmaxf(v[c] * scl[c] + shf[c], 0.f) * pr[c];
}

extern "C" void kernel_launch(void* const* d_in, const int* in_sizes, int n_in,
                              void* d_out, int out_size, void* d_ws, size_t ws_size,
                              hipStream_t stream)
{
    const float* anchor  = (const float*)d_in[0];
    const float* support = (const float*)d_in[1];
    const float* cw  = (const float*)d_in[2];
    const float* cb  = (const float*)d_in[3];
    const float* cgm = (const float*)d_in[4];
    const float* cbt = (const float*)d_in[5];
    const float* pw  = (const float*)d_in[6];
    const float* pb  = (const float*)d_in[7];
    const float* pg  = (const float*)d_in[8];
    const float* pbt = (const float*)d_in[9];
    const float* jw  = (const float*)d_in[10];
    const float* jb  = (const float*)d_in[11];
    const float* jg  = (const float*)d_in[12];
    const float* jbt = (const float*)d_in[13];
    const float* rw  = (const float*)d_in[14];
    const float* rb  = (const float*)d_in[15];
    const float* rg  = (const float*)d_in[16];
    const float* rbt = (const float*)d_in[17];
    float* out = (float*)d_out;

    char* ws = (char*)d_ws;
    // spad [0, 49.2MB) dead after pe_fused -> pre_j/proj overlay it.
    // apad [49.2MB, 51.6MB) dead after conv_main -> deeppad overlays it.
    unsigned short* spad    = (unsigned short*)ws;
    unsigned short* pre_j   = (unsigned short*)(ws + 2458624);           // overlay (post-pe)
    float*          proj    = (float*)(ws + 4817920);                    // overlay (post-pe)
    unsigned short* apad    = (unsigned short*)(ws + 49172480);          // 2,458,624
    unsigned short* deeppad = apad;                                      // overlay (post conv_main)
    unsigned short* sxpe    = (unsigned short*)(ws + 51631104);          // 47,185,920
    unsigned short* srp     = (unsigned short*)(ws + 98817024);          // 11,796,480
    unsigned short* axp     = (unsigned short*)(ws + 110613504);         // 589,824
    unsigned short* frag    = (unsigned short*)(ws + 115921920);         // 15,360
    float*          stats   = (float*)(ws + 115937280);                  // 3,072

    unsigned short* fragR = frag;
    unsigned short* fragC = frag + 5 * 64 * 8;
    unsigned short* fragJ = frag + 10 * 64 * 8;
    float* statsAx = stats,      *statsSr = stats + 32, *statsSx = stats + 64;
    float* statsPe = stats + 96, *statsJ  = stats + 736;

    pack_kernel<<<6308, 256, 0, stream>>>(support, anchor, spad, apad, rw, cw, jw, frag, stats);
    conv_main_kernel<<<2016, 256, 0, stream>>>(spad, apad, fragR, rb, fragC, cb,
                                               srp, sxpe, axp, statsSr, statsSx, statsAx);
    // apad dead from here: deeppad overlays it (halo zeroed inside pe_fused)
    pe_fused_kernel<<<1152, 256, 0, stream>>>(spad, sxpe, statsSx, cgm, cbt, pw, pb,
                                              statsPe, deeppad);
    // spad dead from here: pre_j / proj overlay it
    deep_kernel<<<1152, 256, 0, stream>>>(sxpe, statsPe, pg, pbt, deeppad);
    conv_j_kernel<<<96, 256, 0, stream>>>(deeppad, fragJ, jb, pre_j, statsJ);
    proj_kernel<<<72, 256, 0, stream>>>(pre_j, statsJ, jg, jbt, proj);
    out_kernel<<<1512, 256, 0, stream>>>(srp, axp, statsSr, statsAx, rg, rbt, proj,
                                         out + 294912, out);
}

// Round 10
// 140.956 us; speedup vs baseline: 1.1665x; 1.1665x over previous
//
#include <hip/hip_runtime.h>
#include <stdint.h>

#define EPS_BN 1e-5f

typedef __attribute__((ext_vector_type(8))) short short8;
typedef __attribute__((ext_vector_type(4))) float floatx4;

__device__ __forceinline__ unsigned short f2bf(float f) {
    unsigned u = __builtin_bit_cast(unsigned, f);
    u += 0x7fffu + ((u >> 16) & 1u);   // RNE
    return (unsigned short)(u >> 16);
}
__device__ __forceinline__ float bf2f(unsigned short h) {
    unsigned u = ((unsigned)h) << 16;
    return __builtin_bit_cast(float, u);
}
__device__ __forceinline__ void unpack8(uint4 q, float* v) {
    v[0] = bf2f((unsigned short)q.x); v[1] = bf2f((unsigned short)(q.x >> 16));
    v[2] = bf2f((unsigned short)q.y); v[3] = bf2f((unsigned short)(q.y >> 16));
    v[4] = bf2f((unsigned short)q.z); v[5] = bf2f((unsigned short)(q.z >> 16));
    v[6] = bf2f((unsigned short)q.w); v[7] = bf2f((unsigned short)(q.w >> 16));
}
__device__ __forceinline__ uint4 pack8(const float* v) {
    uint4 q;
    q.x = (unsigned)f2bf(v[0]) | ((unsigned)f2bf(v[1]) << 16);
    q.y = (unsigned)f2bf(v[2]) | ((unsigned)f2bf(v[3]) << 16);
    q.z = (unsigned)f2bf(v[4]) | ((unsigned)f2bf(v[5]) << 16);
    q.w = (unsigned)f2bf(v[6]) | ((unsigned)f2bf(v[7]) << 16);
    return q;
}

__device__ __forceinline__ void async_copy16(const unsigned short* g, unsigned short* l) {
    __builtin_amdgcn_global_load_lds(
        (const __attribute__((address_space(1))) unsigned int*)(const void*)g,
        (__attribute__((address_space(3))) unsigned int*)(void*)l,
        16, 0, 0);
}

// scale = g*rsqrt(var+eps), shift = b - mean*scale, from raw sum/sumsq
__device__ __forceinline__ void bn_coef(const float* st, int n, int c, float invN,
                                        const float* gg, const float* bb,
                                        float* scl, float* shf) {
    const float mean = st[c] * invN;
    const float var = st[n + c] * invN - mean * mean;
    const float sc = gg[c & 15] * rsqrtf(var + EPS_BN);
    scl[c] = sc;
    shf[c] = bb[c & 15] - mean * sc;
}

// =====================================================================
// pack: fp32 NCHW -> padded (halo-zeroed) bf16 NHWC, ch-half swizzled by
// (paddedcol>>2)&1. Blocks >= 6303 do weight fragments + stats zero.
// =====================================================================
__global__ __launch_bounds__(256)
void pack_kernel(const float* __restrict__ support, const float* __restrict__ anchor,
                 unsigned short* __restrict__ spad, unsigned short* __restrict__ apad,
                 const float* __restrict__ rw, const float* __restrict__ cw,
                 const float* __restrict__ jw, unsigned short* __restrict__ frag,
                 float* __restrict__ stats)
{
    const int tid = threadIdx.x;
    if (blockIdx.x >= 6303) {
        const int bx = blockIdx.x - 6303;
        if (bx == 4) {
            #pragma unroll
            for (int k = 0; k < 3; ++k) stats[k * 256 + tid] = 0.f;
            return;
        }
        const int idx = bx * 256 + tid;
        if (idx >= 960) return;
        const int combo = idx >> 6, lane = idx & 63;
        const int cv = combo / 5, j = combo - cv * 5;
        const float* w = (cv == 0) ? rw : (cv == 1) ? cw : jw;
        const int o = lane & 15, g = lane >> 4;
        unsigned short e8[8];
        #pragma unroll
        for (int e = 0; e < 8; ++e) {
            const int k = j * 32 + g * 8 + e;
            unsigned short val = 0;
            if (k < 144) {
                const int t = k >> 4, i = k & 15;
                const int kh = t / 3, kw = t - kh * 3;
                val = f2bf(w[((o * 16 + i) * 3 + kh) * 3 + kw]);
            }
            e8[e] = val;
        }
        *(uint4*)(frag + ((size_t)combo * 64 + lane) * 8) =
            make_uint4((unsigned)e8[0] | ((unsigned)e8[1] << 16), (unsigned)e8[2] | ((unsigned)e8[3] << 16),
                       (unsigned)e8[4] | ((unsigned)e8[5] << 16), (unsigned)e8[6] | ((unsigned)e8[7] << 16));
        return;
    }
    const int idx = blockIdx.x * 256 + tid;
    if (idx >= 168 * 9604) return;
    const int img = idx / 9604;
    const int rem = idx - img * 9604;
    const int pr = rem / 98, pc = rem - pr * 98;
    const int gh = pr - 1, gw = pc - 1;
    const bool ok = (gh >= 0) & (gh < 96) & (gw >= 0) & (gw < 96);
    const float* src = (img < 160) ? (support + (size_t)img * 147456)
                                   : (anchor + (size_t)(img - 160) * 147456);
    unsigned short* dst = (img < 160) ? (spad + (size_t)img * 9604 * 16)
                                      : (apad + (size_t)(img - 160) * 9604 * 16);
    const int gbase = gh * 96 + gw;
    unsigned pk[8];
    #pragma unroll
    for (int c = 0; c < 8; ++c) {
        const float v0 = ok ? src[(2 * c) * 9216 + gbase] : 0.f;
        const float v1 = ok ? src[(2 * c + 1) * 9216 + gbase] : 0.f;
        pk[c] = (unsigned)f2bf(v0) | ((unsigned)f2bf(v1) << 16);
    }
    const int sw = (pc >> 2) & 1;
    unsigned short* p = dst + (size_t)rem * 16;
    *(uint4*)(p + (sw << 3)) = make_uint4(pk[0], pk[1], pk[2], pk[3]);       // ch 0..7
    *(uint4*)(p + ((sw ^ 1) << 3)) = make_uint4(pk[4], pk[5], pk[6], pk[7]); // ch 8..15
}

// =====================================================================
// conv 3x3 pad1 via MFMA (A=weights 16o x k, B=pixels k x 16pix).
// POOLA templated (2x2 maxpool pre-BN on A output), `two` runtime.
// =====================================================================
template<bool POOLA>
__device__ __forceinline__ void conv_tile(
    unsigned short* lds, float* red,
    const unsigned short* __restrict__ imgin,
    const unsigned short* __restrict__ fragA, const float* __restrict__ bA,
    const unsigned short* __restrict__ fragB, const float* __restrict__ bB,
    unsigned short* __restrict__ outAimg, unsigned short* __restrict__ outBimg,
    float* __restrict__ statsA, float* __restrict__ statsB,
    const int r0b, const bool two)
{
    const int tid = threadIdx.x;
    const int lane = tid & 63;
    const int wv = tid >> 6;

    const unsigned short* gsrc = imgin + (size_t)(r0b * 8 * 98) * 16;
    #pragma unroll
    for (int k = 0; k < 8; ++k) {
        const int chunk = k * 256 + tid;
        if (chunk < 1960)
            async_copy16(gsrc + (size_t)chunk * 8, lds + (k * 256 + wv * 64) * 8);
    }

    const int n = lane & 15, g = lane >> 4;
    short8 fA[5], fB[5];
    #pragma unroll
    for (int j = 0; j < 5; ++j) {
        fA[j] = *(const short8*)(fragA + ((size_t)j * 64 + lane) * 8);
        if (two) fB[j] = *(const short8*)(fragB + ((size_t)j * 64 + lane) * 8);
    }
    const float4 bA4 = *(const float4*)(bA + 4 * g);
    float4 bB4 = make_float4(0.f, 0.f, 0.f, 0.f);
    if (two) bB4 = *(const float4*)(bB + 4 * g);
    const float biasA[4] = {bA4.x, bA4.y, bA4.z, bA4.w};
    const float biasB[4] = {bB4.x, bB4.y, bB4.z, bB4.w};

    __syncthreads();

    float s1A[4] = {0.f, 0.f, 0.f, 0.f}, s2A[4] = {0.f, 0.f, 0.f, 0.f};
    float s1B[4] = {0.f, 0.f, 0.f, 0.f}, s2B[4] = {0.f, 0.f, 0.f, 0.f};

    for (int cg = 0; cg < 6; ++cg) {
        float pA[2][4], pB[2][4];
        #pragma unroll
        for (int tr = 0; tr < 2; ++tr) {
            const int lr = 2 * wv + tr;
            floatx4 aA = {0.f, 0.f, 0.f, 0.f};
            floatx4 aB = {0.f, 0.f, 0.f, 0.f};
            #pragma unroll
            for (int j = 0; j < 5; ++j) {
                const int t = (j < 4) ? (2 * j + (g >> 1)) : 8;
                const int kh = t / 3, kw = t - kh * 3;
                const int ldscol = cg * 16 + n + kw;
                const int half = (g & 1) ^ ((ldscol >> 2) & 1);
                const short8 a = *(const short8*)&lds[((lr + kh) * 98 + ldscol) * 16 + (half << 3)];
                aA = __builtin_amdgcn_mfma_f32_16x16x32_bf16(fA[j], a, aA, 0, 0, 0);
                if (two) aB = __builtin_amdgcn_mfma_f32_16x16x32_bf16(fB[j], a, aB, 0, 0, 0);
            }
            #pragma unroll
            for (int r = 0; r < 4; ++r) {
                const float vA = aA[r] + biasA[r];
                pA[tr][r] = vA; s1A[r] += vA; s2A[r] += vA * vA;
                if (two) {
                    const float vB = aB[r] + biasB[r];
                    pB[tr][r] = vB; s1B[r] += vB; s2B[r] += vB * vB;
                }
            }
            const int grow = r0b * 8 + lr;
            const size_t pixbase = ((size_t)(grow * 96 + cg * 16 + n)) * 16 + 4 * g;
            if (two)
                *(uint2*)(outBimg + pixbase) =
                    make_uint2((unsigned)f2bf(pB[tr][0]) | ((unsigned)f2bf(pB[tr][1]) << 16),
                               (unsigned)f2bf(pB[tr][2]) | ((unsigned)f2bf(pB[tr][3]) << 16));
            if (!POOLA)
                *(uint2*)(outAimg + pixbase) =
                    make_uint2((unsigned)f2bf(pA[tr][0]) | ((unsigned)f2bf(pA[tr][1]) << 16),
                               (unsigned)f2bf(pA[tr][2]) | ((unsigned)f2bf(pA[tr][3]) << 16));
        }
        if (POOLA) {
            float pm[4];
            #pragma unroll
            for (int r = 0; r < 4; ++r) {
                pm[r] = fmaxf(pA[0][r], pA[1][r]);
                pm[r] = fmaxf(pm[r], __shfl_xor(pm[r], 1));
            }
            if (!(n & 1)) {
                const int orow = r0b * 4 + wv;
                const size_t ob = ((size_t)(orow * 48 + cg * 8 + (n >> 1))) * 16 + 4 * g;
                *(uint2*)(outAimg + ob) =
                    make_uint2((unsigned)f2bf(pm[0]) | ((unsigned)f2bf(pm[1]) << 16),
                               (unsigned)f2bf(pm[2]) | ((unsigned)f2bf(pm[3]) << 16));
            }
        }
    }

    #pragma unroll
    for (int r = 0; r < 4; ++r) {
        #pragma unroll
        for (int d = 1; d < 16; d <<= 1) {
            s1A[r] += __shfl_xor(s1A[r], d); s2A[r] += __shfl_xor(s2A[r], d);
            if (two) { s1B[r] += __shfl_xor(s1B[r], d); s2B[r] += __shfl_xor(s2B[r], d); }
        }
    }
    if (n == 0) {
        #pragma unroll
        for (int r = 0; r < 4; ++r) {
            red[(wv * 4 + 0) * 16 + g * 4 + r] = s1A[r];
            red[(wv * 4 + 1) * 16 + g * 4 + r] = s2A[r];
            if (two) {
                red[(wv * 4 + 2) * 16 + g * 4 + r] = s1B[r];
                red[(wv * 4 + 3) * 16 + g * 4 + r] = s2B[r];
            }
        }
    }
    __syncthreads();
    if (tid < (two ? 64 : 32)) {
        const int st = tid >> 4, oc = tid & 15;
        const float v = red[(0 * 4 + st) * 16 + oc] + red[(1 * 4 + st) * 16 + oc] +
                        red[(2 * 4 + st) * 16 + oc] + red[(3 * 4 + st) * 16 + oc];
        float* dst = (st < 2) ? statsA : statsB;
        atomicAdd(&dst[(st & 1) * 16 + oc], v);
    }
}

// main conv: blocks [0,1920) = support (dual conv), [1920,2016) = anchor
__global__ __launch_bounds__(256)
void conv_main_kernel(const unsigned short* __restrict__ spad, const unsigned short* __restrict__ apad,
                      const unsigned short* __restrict__ fragR, const float* __restrict__ rb,
                      const unsigned short* __restrict__ fragC, const float* __restrict__ cb,
                      unsigned short* __restrict__ srp, unsigned short* __restrict__ sxpe,
                      unsigned short* __restrict__ axp,
                      float* __restrict__ statsSr, float* __restrict__ statsSx,
                      float* __restrict__ statsAx)
{
    __shared__ __align__(16) unsigned short lds[10 * 98 * 16];
    __shared__ float red[4 * 4 * 16];
    const bool two = blockIdx.x < 1920;
    const int bid = two ? blockIdx.x : blockIdx.x - 1920;
    const int img = bid / 12;
    const int r0b = bid - img * 12;
    const unsigned short* in = (two ? spad : apad) + (size_t)img * 9604 * 16;
    unsigned short* outA = (two ? srp : axp) + (size_t)img * 2304 * 16;
    unsigned short* outB = sxpe + (size_t)img * 9216 * 16;
    conv_tile<true>(lds, red, in, fragR, rb, fragC, cb, outA, outB,
                    two ? statsSr : statsAx, statsSx, r0b, two);
}

// projector conv (deep -> pre_j, unpooled)
__global__ __launch_bounds__(256)
void conv_j_kernel(const unsigned short* __restrict__ deeppad,
                   const unsigned short* __restrict__ fragJ, const float* __restrict__ jb,
                   unsigned short* __restrict__ pre_j, float* __restrict__ statsJ)
{
    __shared__ __align__(16) unsigned short lds[10 * 98 * 16];
    __shared__ float red[4 * 4 * 16];
    const int img = blockIdx.x / 12;
    const int r0b = blockIdx.x - img * 12;
    conv_tile<false>(lds, red, deeppad + (size_t)img * 9604 * 16, fragJ, jb, nullptr, nullptr,
                     pre_j + (size_t)img * 9216 * 16, nullptr, statsJ, nullptr, r0b, false);
}

// ---------------- sxsum[b][pix][c] = sum_s relu(bn(sx)); 4-way s split;
// blocks 0..12 also zero the deeppad halo ring
__global__ __launch_bounds__(256)
void sxsum_kernel(const unsigned short* __restrict__ sx, const float* __restrict__ statsSx,
                  const float* __restrict__ cgm, const float* __restrict__ cbt,
                  float* __restrict__ out, unsigned short* __restrict__ deeppad)
{
    __shared__ float scl[16], shf[16];
    __shared__ float part[3][64][17];
    const int tid = threadIdx.x;
    if (blockIdx.x < 13) {
        const int idx = blockIdx.x * 256 + tid;
        if (idx < 8 * 388) {
            const int img = idx / 388;
            const int h = idx - img * 388;
            int pr, pc;
            if (h < 98)       { pr = 0;           pc = h; }
            else if (h < 196) { pr = 97;          pc = h - 98; }
            else if (h < 292) { pr = h - 196 + 1; pc = 0; }
            else              { pr = h - 292 + 1; pc = 97; }
            unsigned short* p = deeppad + ((size_t)img * 9604 + pr * 98 + pc) * 16;
            *(uint4*)p = make_uint4(0, 0, 0, 0);
            *(uint4*)(p + 8) = make_uint4(0, 0, 0, 0);
        }
    }
    if (tid < 16) bn_coef(statsSx, 16, tid, 1.f / 1474560.f, cgm, cbt, scl, shf);
    const int b = blockIdx.x / 144;
    const int chunk = blockIdx.x - b * 144;
    const int px = tid & 63, sg = tid >> 6;
    const int pix = chunk * 64 + px;
    __syncthreads();
    float acc[16];
    #pragma unroll
    for (int c = 0; c < 16; ++c) acc[c] = 0.f;
    const unsigned short* p = sx + ((size_t)(b * 20 + sg * 5) * 9216 + pix) * 16;
    #pragma unroll
    for (int s = 0; s < 5; ++s) {
        float v[16];
        unpack8(*(const uint4*)p, v);
        unpack8(*(const uint4*)(p + 8), v + 8);
        #pragma unroll
        for (int c = 0; c < 16; ++c) acc[c] += fmaxf(v[c] * scl[c] + shf[c], 0.f);
        p += 9216 * 16;
    }
    if (sg > 0) {
        #pragma unroll
        for (int c = 0; c < 16; ++c) part[sg - 1][px][c] = acc[c];
    }
    __syncthreads();
    if (sg == 0) {
        #pragma unroll
        for (int c = 0; c < 16; ++c) acc[c] += part[0][px][c] + part[1][px][c] + part[2][px][c];
        float* o = out + ((size_t)b * 9216 + pix) * 16;
        #pragma unroll
        for (int q = 0; q < 4; ++q)
            *(float4*)(o + 4 * q) = make_float4(acc[4 * q], acc[4 * q + 1], acc[4 * q + 2], acc[4 * q + 3]);
    }
}

// =====================================================================
// pe = 1x1 conv [support; loo] via ONE mfma per 16 pixels + fused per-(s,c)
// stats (channels live in registers -> 4 shfl steps over pixel lanes).
// 512 px per block (2880 blocks) for latency hiding.
// =====================================================================
__global__ __launch_bounds__(256)
void pe_kernel(const unsigned short* __restrict__ spad, unsigned short* __restrict__ sxpe,
               const float* __restrict__ sxsum, const float* __restrict__ statsSx,
               const float* __restrict__ cgm, const float* __restrict__ cbt,
               const float* __restrict__ pw, const float* __restrict__ pb,
               float* __restrict__ statsPe)
{
    __shared__ float sscl[16], sshf[16];
    __shared__ float red[4][2][16];
    const int tid = threadIdx.x;
    if (tid < 16) bn_coef(statsSx, 16, tid, 1.f / 1474560.f, cgm, cbt, sscl, sshf);
    const int lane = tid & 63, wv = tid >> 6;
    const int p = lane & 15, g = lane >> 4;
    const int img = blockIdx.x / 18;
    const int chunk = blockIdx.x - img * 18;
    const int b = img / 20, s = img - b * 20;
    const int c0 = (g & 1) * 8;

    short8 fw;
    {
        const float4 wa = *(const float4*)(pw + p * 32 + g * 8);
        const float4 wb = *(const float4*)(pw + p * 32 + g * 8 + 4);
        fw[0] = (short)f2bf(wa.x); fw[1] = (short)f2bf(wa.y);
        fw[2] = (short)f2bf(wa.z); fw[3] = (short)f2bf(wa.w);
        fw[4] = (short)f2bf(wb.x); fw[5] = (short)f2bf(wb.y);
        fw[6] = (short)f2bf(wb.z); fw[7] = (short)f2bf(wb.w);
    }
    const float4 b4 = *(const float4*)(pb + 4 * g);
    const float bias[4] = {b4.x, b4.y, b4.z, b4.w};
    __syncthreads();
    float scl[8], shf[8];
    #pragma unroll
    for (int e = 0; e < 8; ++e) { scl[e] = sscl[c0 + e]; shf[e] = sshf[c0 + e]; }

    const unsigned short* imgspad = spad + (size_t)img * 9604 * 16;
    unsigned short* imgsx = sxpe + (size_t)img * 9216 * 16;
    const float* bsum = sxsum + (size_t)b * 9216 * 16;

    float s1[4] = {0.f, 0.f, 0.f, 0.f}, s2[4] = {0.f, 0.f, 0.f, 0.f};

    for (int it = 0; it < 8; ++it) {
        const int pix = chunk * 512 + it * 64 + wv * 16 + p;
        short8 bf;
        if (g < 2) {
            const int row = pix / 96, col = pix - row * 96;
            const int sw = ((col + 1) >> 2) & 1;
            bf = *(const short8*)(imgspad + ((row + 1) * 98 + col + 1) * 16 + (((g ^ sw) & 1) << 3));
        } else {
            float xv[8];
            unpack8(*(const uint4*)(imgsx + (size_t)pix * 16 + c0), xv);
            const float* sm = bsum + (size_t)pix * 16 + c0;
            const float4 sma = *(const float4*)sm;
            const float4 smb = *(const float4*)(sm + 4);
            const float smv[8] = {sma.x, sma.y, sma.z, sma.w, smb.x, smb.y, smb.z, smb.w};
            #pragma unroll
            for (int e = 0; e < 8; ++e) {
                const float loo = smv[e] - fmaxf(xv[e] * scl[e] + shf[e], 0.f);
                bf[e] = (short)f2bf(loo);
            }
        }
        floatx4 acc = {0.f, 0.f, 0.f, 0.f};
        acc = __builtin_amdgcn_mfma_f32_16x16x32_bf16(fw, bf, acc, 0, 0, 0);
        const float v0 = acc[0] + bias[0], v1 = acc[1] + bias[1];
        const float v2 = acc[2] + bias[2], v3 = acc[3] + bias[3];
        s1[0] += v0; s1[1] += v1; s1[2] += v2; s1[3] += v3;
        s2[0] += v0 * v0; s2[1] += v1 * v1; s2[2] += v2 * v2; s2[3] += v3 * v3;
        *(uint2*)(imgsx + (size_t)pix * 16 + 4 * g) =
            make_uint2((unsigned)f2bf(v0) | ((unsigned)f2bf(v1) << 16),
                       (unsigned)f2bf(v2) | ((unsigned)f2bf(v3) << 16));
    }

    #pragma unroll
    for (int r = 0; r < 4; ++r) {
        #pragma unroll
        for (int d = 1; d < 16; d <<= 1) {
            s1[r] += __shfl_xor(s1[r], d);
            s2[r] += __shfl_xor(s2[r], d);
        }
    }
    if (p == 0) {
        #pragma unroll
        for (int r = 0; r < 4; ++r) { red[wv][0][g * 4 + r] = s1[r]; red[wv][1][g * 4 + r] = s2[r]; }
    }
    __syncthreads();
    if (tid < 32) {
        const int st = tid >> 4, c = tid & 15;
        const float v = red[0][st][c] + red[1][st][c] + red[2][st][c] + red[3][st][c];
        atomicAdd(&statsPe[st * 320 + s * 16 + c], v);
    }
}

// ---------------- deep: mean_s relu(bn_{s,c}(pe)), 4-way s split, coef prologue
__global__ __launch_bounds__(256)
void deep_kernel(const unsigned short* __restrict__ pe, const float* __restrict__ statsPe,
                 const float* __restrict__ pg, const float* __restrict__ pbt,
                 unsigned short* __restrict__ deeppad)
{
    __shared__ float scl[320], shf[320];
    __shared__ float part[3][64][17];
    const int tid = threadIdx.x;
    for (int i = tid; i < 320; i += 256)
        bn_coef(statsPe, 320, i, 1.f / 73728.f, pg, pbt, scl, shf);
    const int b = blockIdx.x / 144;
    const int chunk = blockIdx.x - b * 144;
    const int px = tid & 63, sg = tid >> 6;
    const int pix = chunk * 64 + px;
    __syncthreads();
    float acc[16];
    #pragma unroll
    for (int c = 0; c < 16; ++c) acc[c] = 0.f;
    const unsigned short* p = pe + ((size_t)(b * 20 + sg * 5) * 9216 + pix) * 16;
    #pragma unroll
    for (int s = 0; s < 5; ++s) {
        const int si = sg * 5 + s;
        float v[16];
        unpack8(*(const uint4*)p, v);
        unpack8(*(const uint4*)(p + 8), v + 8);
        #pragma unroll
        for (int c = 0; c < 16; ++c) acc[c] += fmaxf(v[c] * scl[si * 16 + c] + shf[si * 16 + c], 0.f);
        p += 9216 * 16;
    }
    if (sg > 0) {
        #pragma unroll
        for (int c = 0; c < 16; ++c) part[sg - 1][px][c] = acc[c];
    }
    __syncthreads();
    if (sg == 0) {
        #pragma unroll
        for (int c = 0; c < 16; ++c)
            acc[c] = (acc[c] + part[0][px][c] + part[1][px][c] + part[2][px][c]) * 0.05f;
        const int row = pix / 96, col = pix - row * 96;
        const int sw = ((col + 1) >> 2) & 1;
        unsigned short* d = deeppad + ((size_t)b * 9604 + (row + 1) * 98 + col + 1) * 16;
        *(uint4*)(d + (sw << 3)) = pack8(acc);
        *(uint4*)(d + ((sw ^ 1) << 3)) = pack8(acc + 8);
    }
}

// ---------------- proj = maxpool2(softmax_ch(bn(conv_j))), coef prologue
__global__ __launch_bounds__(256)
void proj_kernel(const unsigned short* __restrict__ pj, const float* __restrict__ statsJ,
                 const float* __restrict__ jg, const float* __restrict__ jbt,
                 float* __restrict__ proj)
{
    __shared__ float scl[16], shf[16];
    const int tid = threadIdx.x;
    if (tid < 16) bn_coef(statsJ, 16, tid, 1.f / 73728.f, jg, jbt, scl, shf);
    const int b = blockIdx.x / 9;
    const int opix = (blockIdx.x - b * 9) * 256 + tid;
    __syncthreads();
    const int oi = opix / 48, oj = opix - oi * 48;
    float mx[16];
    #pragma unroll
    for (int c = 0; c < 16; ++c) mx[c] = 0.f;
    #pragma unroll
    for (int dy = 0; dy < 2; ++dy) {
        const unsigned short* q = pj + ((size_t)b * 9216 + (2 * oi + dy) * 96 + 2 * oj) * 16;
        #pragma unroll
        for (int dx = 0; dx < 2; ++dx) {
            float v[16]; float mval = -1e30f;
            unpack8(*(const uint4*)(q + dx * 16), v);
            unpack8(*(const uint4*)(q + dx * 16 + 8), v + 8);
            #pragma unroll
            for (int c = 0; c < 16; ++c) { v[c] = v[c] * scl[c] + shf[c]; mval = fmaxf(mval, v[c]); }
            float ssum = 0.f;
            #pragma unroll
            for (int c = 0; c < 16; ++c) { v[c] = __expf(v[c] - mval); ssum += v[c]; }
            const float inv = 1.f / ssum;
            #pragma unroll
            for (int c = 0; c < 16; ++c) mx[c] = fmaxf(mx[c], v[c] * inv);
        }
    }
    float* o = proj + ((size_t)b * 2304 + opix) * 16;
    #pragma unroll
    for (int q2 = 0; q2 < 4; ++q2)
        *(float4*)(o + 4 * q2) = make_float4(mx[4 * q2], mx[4 * q2 + 1], mx[4 * q2 + 2], mx[4 * q2 + 3]);
}

// ---------------- merged outputs: blocks [0,1440) support, [1440,1512) anchor
__global__ __launch_bounds__(256)
void out_kernel(const unsigned short* __restrict__ srp, const unsigned short* __restrict__ axp,
                const float* __restrict__ statsSr, const float* __restrict__ statsAx,
                const float* __restrict__ rg, const float* __restrict__ rbt,
                const float* __restrict__ proj, float* __restrict__ outS,
                float* __restrict__ outA)
{
    __shared__ float scl[16], shf[16];
    const int tid = threadIdx.x;
    const bool sup = blockIdx.x < 1440;
    if (tid < 16) {
        if (sup) bn_coef(statsSr, 16, tid, 1.f / 1474560.f, rg, rbt, scl, shf);
        else     bn_coef(statsAx, 16, tid, 1.f / 73728.f, rg, rbt, scl, shf);
    }
    const int bid = sup ? blockIdx.x : blockIdx.x - 1440;
    const int bs = bid / 9;
    const int opix = (bid - bs * 9) * 256 + tid;
    const int b = sup ? bs / 20 : bs;
    __syncthreads();
    const unsigned short* p = (sup ? srp : axp) + ((size_t)bs * 2304 + opix) * 16;
    float v[16];
    unpack8(*(const uint4*)p, v);
    unpack8(*(const uint4*)(p + 8), v + 8);
    const float* pr = proj + ((size_t)b * 2304 + opix) * 16;
    float* o = sup ? outS : outA;
    #pragma unroll
    for (int c = 0; c < 16; ++c)
        o[((size_t)bs * 16 + c) * 2304 + opix] = fmaxf(v[c] * scl[c] + shf[c], 0.f) * pr[c];
}

extern "C" void kernel_launch(void* const* d_in, const int* in_sizes, int n_in,
                              void* d_out, int out_size, void* d_ws, size_t ws_size,
                              hipStream_t stream)
{
    const float* anchor  = (const float*)d_in[0];
    const float* support = (const float*)d_in[1];
    const float* cw  = (const float*)d_in[2];
    const float* cb  = (const float*)d_in[3];
    const float* cgm = (const float*)d_in[4];
    const float* cbt = (const float*)d_in[5];
    const float* pw  = (const float*)d_in[6];
    const float* pb  = (const float*)d_in[7];
    const float* pg  = (const float*)d_in[8];
    const float* pbt = (const float*)d_in[9];
    const float* jw  = (const float*)d_in[10];
    const float* jb  = (const float*)d_in[11];
    const float* jg  = (const float*)d_in[12];
    const float* jbt = (const float*)d_in[13];
    const float* rw  = (const float*)d_in[14];
    const float* rb  = (const float*)d_in[15];
    const float* rg  = (const float*)d_in[16];
    const float* rbt = (const float*)d_in[17];
    float* out = (float*)d_out;

    char* ws = (char*)d_ws;
    // spad [0, 49.2MB) dead after pe -> pre_j/proj overlay it.
    // apad [49.2MB, 51.6MB) dead after conv_main -> deeppad overlays it.
    unsigned short* spad    = (unsigned short*)ws;
    unsigned short* pre_j   = (unsigned short*)(ws + 2458624);           // overlay (post-pe)
    float*          proj    = (float*)(ws + 4817920);                    // overlay (post-pe)
    unsigned short* apad    = (unsigned short*)(ws + 49172480);          // 2,458,624
    unsigned short* deeppad = apad;                                      // overlay (post conv_main)
    unsigned short* sxpe    = (unsigned short*)(ws + 51631104);          // 47,185,920
    unsigned short* srp     = (unsigned short*)(ws + 98817024);          // 11,796,480
    unsigned short* axp     = (unsigned short*)(ws + 110613504);         // 589,824
    float*          sxsum   = (float*)(ws + 111203328);                  // 4,718,592
    unsigned short* frag    = (unsigned short*)(ws + 115921920);         // 15,360
    float*          stats   = (float*)(ws + 115937280);                  // 3,072

    unsigned short* fragR = frag;
    unsigned short* fragC = frag + 5 * 64 * 8;
    unsigned short* fragJ = frag + 10 * 64 * 8;
    float* statsAx = stats,      *statsSr = stats + 32, *statsSx = stats + 64;
    float* statsPe = stats + 96, *statsJ  = stats + 736;

    pack_kernel<<<6308, 256, 0, stream>>>(support, anchor, spad, apad, rw, cw, jw, frag, stats);
    conv_main_kernel<<<2016, 256, 0, stream>>>(spad, apad, fragR, rb, fragC, cb,
                                               srp, sxpe, axp, statsSr, statsSx, statsAx);
    // apad dead from here: deeppad overlays it (halo zeroed inside sxsum)
    sxsum_kernel<<<1152, 256, 0, stream>>>(sxpe, statsSx, cgm, cbt, sxsum, deeppad);
    pe_kernel<<<2880, 256, 0, stream>>>(spad, sxpe, sxsum, statsSx, cgm, cbt, pw, pb, statsPe);
    // spad dead from here: pre_j / proj overlay it
    deep_kernel<<<1152, 256, 0, stream>>>(sxpe, statsPe, pg, pbt, deeppad);
    conv_j_kernel<<<96, 256, 0, stream>>>(deeppad, fragJ, jb, pre_j, statsJ);
    proj_kernel<<<72, 256, 0, stream>>>(pre_j, statsJ, jg, jbt, proj);
    out_kernel<<<1512, 256, 0, stream>>>(srp, axp, statsSr, statsAx, rg, rbt, proj,
                                         out + 294912, out);
}

// Round 11
// 139.283 us; speedup vs baseline: 1.1805x; 1.0120x over previous
//
#include <hip/hip_runtime.h>
#include <stdint.h>

#define EPS_BN 1e-5f

typedef __attribute__((ext_vector_type(8))) short short8;
typedef __attribute__((ext_vector_type(4))) float floatx4;

__device__ __forceinline__ unsigned short f2bf(float f) {
    unsigned u = __builtin_bit_cast(unsigned, f);
    u += 0x7fffu + ((u >> 16) & 1u);   // RNE
    return (unsigned short)(u >> 16);
}
__device__ __forceinline__ float bf2f(unsigned short h) {
    unsigned u = ((unsigned)h) << 16;
    return __builtin_bit_cast(float, u);
}
__device__ __forceinline__ void unpack8(uint4 q, float* v) {
    v[0] = bf2f((unsigned short)q.x); v[1] = bf2f((unsigned short)(q.x >> 16));
    v[2] = bf2f((unsigned short)q.y); v[3] = bf2f((unsigned short)(q.y >> 16));
    v[4] = bf2f((unsigned short)q.z); v[5] = bf2f((unsigned short)(q.z >> 16));
    v[6] = bf2f((unsigned short)q.w); v[7] = bf2f((unsigned short)(q.w >> 16));
}
__device__ __forceinline__ uint4 pack8(const float* v) {
    uint4 q;
    q.x = (unsigned)f2bf(v[0]) | ((unsigned)f2bf(v[1]) << 16);
    q.y = (unsigned)f2bf(v[2]) | ((unsigned)f2bf(v[3]) << 16);
    q.z = (unsigned)f2bf(v[4]) | ((unsigned)f2bf(v[5]) << 16);
    q.w = (unsigned)f2bf(v[6]) | ((unsigned)f2bf(v[7]) << 16);
    return q;
}

__device__ __forceinline__ void async_copy16(const unsigned short* g, unsigned short* l) {
    __builtin_amdgcn_global_load_lds(
        (const __attribute__((address_space(1))) unsigned int*)(const void*)g,
        (__attribute__((address_space(3))) unsigned int*)(void*)l,
        16, 0, 0);
}

// scale = g*rsqrt(var+eps), shift = b - mean*scale, from raw sum/sumsq
__device__ __forceinline__ void bn_coef(const float* st, int n, int c, float invN,
                                        const float* gg, const float* bb,
                                        float* scl, float* shf) {
    const float mean = st[c] * invN;
    const float var = st[n + c] * invN - mean * mean;
    const float sc = gg[c & 15] * rsqrtf(var + EPS_BN);
    scl[c] = sc;
    shf[c] = bb[c & 15] - mean * sc;
}

// =====================================================================
// pack: fp32 NCHW -> padded (halo-zeroed) bf16 NHWC, ch-half swizzled by
// (paddedcol>>2)&1. Blocks >= 6303 do weight fragments + stats zero.
// =====================================================================
__global__ __launch_bounds__(256)
void pack_kernel(const float* __restrict__ support, const float* __restrict__ anchor,
                 unsigned short* __restrict__ spad, unsigned short* __restrict__ apad,
                 const float* __restrict__ rw, const float* __restrict__ cw,
                 const float* __restrict__ jw, unsigned short* __restrict__ frag,
                 float* __restrict__ stats)
{
    const int tid = threadIdx.x;
    if (blockIdx.x >= 6303) {
        const int bx = blockIdx.x - 6303;
        if (bx == 4) {
            #pragma unroll
            for (int k = 0; k < 3; ++k) stats[k * 256 + tid] = 0.f;
            return;
        }
        const int idx = bx * 256 + tid;
        if (idx >= 960) return;
        const int combo = idx >> 6, lane = idx & 63;
        const int cv = combo / 5, j = combo - cv * 5;
        const float* w = (cv == 0) ? rw : (cv == 1) ? cw : jw;
        const int o = lane & 15, g = lane >> 4;
        unsigned short e8[8];
        #pragma unroll
        for (int e = 0; e < 8; ++e) {
            const int k = j * 32 + g * 8 + e;
            unsigned short val = 0;
            if (k < 144) {
                const int t = k >> 4, i = k & 15;
                const int kh = t / 3, kw = t - kh * 3;
                val = f2bf(w[((o * 16 + i) * 3 + kh) * 3 + kw]);
            }
            e8[e] = val;
        }
        *(uint4*)(frag + ((size_t)combo * 64 + lane) * 8) =
            make_uint4((unsigned)e8[0] | ((unsigned)e8[1] << 16), (unsigned)e8[2] | ((unsigned)e8[3] << 16),
                       (unsigned)e8[4] | ((unsigned)e8[5] << 16), (unsigned)e8[6] | ((unsigned)e8[7] << 16));
        return;
    }
    const int idx = blockIdx.x * 256 + tid;
    if (idx >= 168 * 9604) return;
    const int img = idx / 9604;
    const int rem = idx - img * 9604;
    const int pr = rem / 98, pc = rem - pr * 98;
    const int gh = pr - 1, gw = pc - 1;
    const bool ok = (gh >= 0) & (gh < 96) & (gw >= 0) & (gw < 96);
    const float* src = (img < 160) ? (support + (size_t)img * 147456)
                                   : (anchor + (size_t)(img - 160) * 147456);
    unsigned short* dst = (img < 160) ? (spad + (size_t)img * 9604 * 16)
                                      : (apad + (size_t)(img - 160) * 9604 * 16);
    const int gbase = gh * 96 + gw;
    unsigned pk[8];
    #pragma unroll
    for (int c = 0; c < 8; ++c) {
        const float v0 = ok ? src[(2 * c) * 9216 + gbase] : 0.f;
        const float v1 = ok ? src[(2 * c + 1) * 9216 + gbase] : 0.f;
        pk[c] = (unsigned)f2bf(v0) | ((unsigned)f2bf(v1) << 16);
    }
    const int sw = (pc >> 2) & 1;
    unsigned short* p = dst + (size_t)rem * 16;
    *(uint4*)(p + (sw << 3)) = make_uint4(pk[0], pk[1], pk[2], pk[3]);       // ch 0..7
    *(uint4*)(p + ((sw ^ 1) << 3)) = make_uint4(pk[4], pk[5], pk[6], pk[7]); // ch 8..15
}

// =====================================================================
// conv 3x3 pad1 via MFMA (A=weights 16o x k, B=pixels k x 16pix).
// POOLA templated (2x2 maxpool pre-BN on A output), `two` runtime.
// =====================================================================
template<bool POOLA>
__device__ __forceinline__ void conv_tile(
    unsigned short* lds, float* red,
    const unsigned short* __restrict__ imgin,
    const unsigned short* __restrict__ fragA, const float* __restrict__ bA,
    const unsigned short* __restrict__ fragB, const float* __restrict__ bB,
    unsigned short* __restrict__ outAimg, unsigned short* __restrict__ outBimg,
    float* __restrict__ statsA, float* __restrict__ statsB,
    const int r0b, const bool two)
{
    const int tid = threadIdx.x;
    const int lane = tid & 63;
    const int wv = tid >> 6;

    const unsigned short* gsrc = imgin + (size_t)(r0b * 8 * 98) * 16;
    #pragma unroll
    for (int k = 0; k < 8; ++k) {
        const int chunk = k * 256 + tid;
        if (chunk < 1960)
            async_copy16(gsrc + (size_t)chunk * 8, lds + (k * 256 + wv * 64) * 8);
    }

    const int n = lane & 15, g = lane >> 4;
    short8 fA[5], fB[5];
    #pragma unroll
    for (int j = 0; j < 5; ++j) {
        fA[j] = *(const short8*)(fragA + ((size_t)j * 64 + lane) * 8);
        if (two) fB[j] = *(const short8*)(fragB + ((size_t)j * 64 + lane) * 8);
    }
    const float4 bA4 = *(const float4*)(bA + 4 * g);
    float4 bB4 = make_float4(0.f, 0.f, 0.f, 0.f);
    if (two) bB4 = *(const float4*)(bB + 4 * g);
    const float biasA[4] = {bA4.x, bA4.y, bA4.z, bA4.w};
    const float biasB[4] = {bB4.x, bB4.y, bB4.z, bB4.w};

    __syncthreads();

    float s1A[4] = {0.f, 0.f, 0.f, 0.f}, s2A[4] = {0.f, 0.f, 0.f, 0.f};
    float s1B[4] = {0.f, 0.f, 0.f, 0.f}, s2B[4] = {0.f, 0.f, 0.f, 0.f};

    for (int cg = 0; cg < 6; ++cg) {
        float pA[2][4], pB[2][4];
        #pragma unroll
        for (int tr = 0; tr < 2; ++tr) {
            const int lr = 2 * wv + tr;
            floatx4 aA = {0.f, 0.f, 0.f, 0.f};
            floatx4 aB = {0.f, 0.f, 0.f, 0.f};
            #pragma unroll
            for (int j = 0; j < 5; ++j) {
                const int t = (j < 4) ? (2 * j + (g >> 1)) : 8;
                const int kh = t / 3, kw = t - kh * 3;
                const int ldscol = cg * 16 + n + kw;
                const int half = (g & 1) ^ ((ldscol >> 2) & 1);
                const short8 a = *(const short8*)&lds[((lr + kh) * 98 + ldscol) * 16 + (half << 3)];
                aA = __builtin_amdgcn_mfma_f32_16x16x32_bf16(fA[j], a, aA, 0, 0, 0);
                if (two) aB = __builtin_amdgcn_mfma_f32_16x16x32_bf16(fB[j], a, aB, 0, 0, 0);
            }
            #pragma unroll
            for (int r = 0; r < 4; ++r) {
                const float vA = aA[r] + biasA[r];
                pA[tr][r] = vA; s1A[r] += vA; s2A[r] += vA * vA;
                if (two) {
                    const float vB = aB[r] + biasB[r];
                    pB[tr][r] = vB; s1B[r] += vB; s2B[r] += vB * vB;
                }
            }
            const int grow = r0b * 8 + lr;
            const size_t pixbase = ((size_t)(grow * 96 + cg * 16 + n)) * 16 + 4 * g;
            if (two)
                *(uint2*)(outBimg + pixbase) =
                    make_uint2((unsigned)f2bf(pB[tr][0]) | ((unsigned)f2bf(pB[tr][1]) << 16),
                               (unsigned)f2bf(pB[tr][2]) | ((unsigned)f2bf(pB[tr][3]) << 16));
            if (!POOLA)
                *(uint2*)(outAimg + pixbase) =
                    make_uint2((unsigned)f2bf(pA[tr][0]) | ((unsigned)f2bf(pA[tr][1]) << 16),
                               (unsigned)f2bf(pA[tr][2]) | ((unsigned)f2bf(pA[tr][3]) << 16));
        }
        if (POOLA) {
            float pm[4];
            #pragma unroll
            for (int r = 0; r < 4; ++r) {
                pm[r] = fmaxf(pA[0][r], pA[1][r]);
                pm[r] = fmaxf(pm[r], __shfl_xor(pm[r], 1));
            }
            if (!(n & 1)) {
                const int orow = r0b * 4 + wv;
                const size_t ob = ((size_t)(orow * 48 + cg * 8 + (n >> 1))) * 16 + 4 * g;
                *(uint2*)(outAimg + ob) =
                    make_uint2((unsigned)f2bf(pm[0]) | ((unsigned)f2bf(pm[1]) << 16),
                               (unsigned)f2bf(pm[2]) | ((unsigned)f2bf(pm[3]) << 16));
            }
        }
    }

    #pragma unroll
    for (int r = 0; r < 4; ++r) {
        #pragma unroll
        for (int d = 1; d < 16; d <<= 1) {
            s1A[r] += __shfl_xor(s1A[r], d); s2A[r] += __shfl_xor(s2A[r], d);
            if (two) { s1B[r] += __shfl_xor(s1B[r], d); s2B[r] += __shfl_xor(s2B[r], d); }
        }
    }
    if (n == 0) {
        #pragma unroll
        for (int r = 0; r < 4; ++r) {
            red[(wv * 4 + 0) * 16 + g * 4 + r] = s1A[r];
            red[(wv * 4 + 1) * 16 + g * 4 + r] = s2A[r];
            if (two) {
                red[(wv * 4 + 2) * 16 + g * 4 + r] = s1B[r];
                red[(wv * 4 + 3) * 16 + g * 4 + r] = s2B[r];
            }
        }
    }
    __syncthreads();
    if (tid < (two ? 64 : 32)) {
        const int st = tid >> 4, oc = tid & 15;
        const float v = red[(0 * 4 + st) * 16 + oc] + red[(1 * 4 + st) * 16 + oc] +
                        red[(2 * 4 + st) * 16 + oc] + red[(3 * 4 + st) * 16 + oc];
        float* dst = (st < 2) ? statsA : statsB;
        atomicAdd(&dst[(st & 1) * 16 + oc], v);
    }
}

// main conv: blocks [0,1920) = support (dual conv), [1920,2016) = anchor
// launch_bounds(256,4): cap 128 VGPR (body measured ~108) -> 4 blocks/CU
__global__ __launch_bounds__(256, 4)
void conv_main_kernel(const unsigned short* __restrict__ spad, const unsigned short* __restrict__ apad,
                      const unsigned short* __restrict__ fragR, const float* __restrict__ rb,
                      const unsigned short* __restrict__ fragC, const float* __restrict__ cb,
                      unsigned short* __restrict__ srp, unsigned short* __restrict__ sxpe,
                      unsigned short* __restrict__ axp,
                      float* __restrict__ statsSr, float* __restrict__ statsSx,
                      float* __restrict__ statsAx)
{
    __shared__ __align__(16) unsigned short lds[10 * 98 * 16];
    __shared__ float red[4 * 4 * 16];
    const bool two = blockIdx.x < 1920;
    const int bid = two ? blockIdx.x : blockIdx.x - 1920;
    const int img = bid / 12;
    const int r0b = bid - img * 12;
    const unsigned short* in = (two ? spad : apad) + (size_t)img * 9604 * 16;
    unsigned short* outA = (two ? srp : axp) + (size_t)img * 2304 * 16;
    unsigned short* outB = sxpe + (size_t)img * 9216 * 16;
    conv_tile<true>(lds, red, in, fragR, rb, fragC, cb, outA, outB,
                    two ? statsSr : statsAx, statsSx, r0b, two);
}

// projector conv (deep -> pre_j, unpooled)
__global__ __launch_bounds__(256, 4)
void conv_j_kernel(const unsigned short* __restrict__ deeppad,
                   const unsigned short* __restrict__ fragJ, const float* __restrict__ jb,
                   unsigned short* __restrict__ pre_j, float* __restrict__ statsJ)
{
    __shared__ __align__(16) unsigned short lds[10 * 98 * 16];
    __shared__ float red[4 * 4 * 16];
    const int img = blockIdx.x / 12;
    const int r0b = blockIdx.x - img * 12;
    conv_tile<false>(lds, red, deeppad + (size_t)img * 9604 * 16, fragJ, jb, nullptr, nullptr,
                     pre_j + (size_t)img * 9216 * 16, nullptr, statsJ, nullptr, r0b, false);
}

// ---------------- sxsum[b][pix][c] = sum_s relu(bn(sx)); 4-way s split;
// blocks 0..12 also zero the deeppad halo ring
__global__ __launch_bounds__(256)
void sxsum_kernel(const unsigned short* __restrict__ sx, const float* __restrict__ statsSx,
                  const float* __restrict__ cgm, const float* __restrict__ cbt,
                  float* __restrict__ out, unsigned short* __restrict__ deeppad)
{
    __shared__ float scl[16], shf[16];
    __shared__ float part[3][64][17];
    const int tid = threadIdx.x;
    if (blockIdx.x < 13) {
        const int idx = blockIdx.x * 256 + tid;
        if (idx < 8 * 388) {
            const int img = idx / 388;
            const int h = idx - img * 388;
            int pr, pc;
            if (h < 98)       { pr = 0;           pc = h; }
            else if (h < 196) { pr = 97;          pc = h - 98; }
            else if (h < 292) { pr = h - 196 + 1; pc = 0; }
            else              { pr = h - 292 + 1; pc = 97; }
            unsigned short* p = deeppad + ((size_t)img * 9604 + pr * 98 + pc) * 16;
            *(uint4*)p = make_uint4(0, 0, 0, 0);
            *(uint4*)(p + 8) = make_uint4(0, 0, 0, 0);
        }
    }
    if (tid < 16) bn_coef(statsSx, 16, tid, 1.f / 1474560.f, cgm, cbt, scl, shf);
    const int b = blockIdx.x / 144;
    const int chunk = blockIdx.x - b * 144;
    const int px = tid & 63, sg = tid >> 6;
    const int pix = chunk * 64 + px;
    __syncthreads();
    float acc[16];
    #pragma unroll
    for (int c = 0; c < 16; ++c) acc[c] = 0.f;
    const unsigned short* p = sx + ((size_t)(b * 20 + sg * 5) * 9216 + pix) * 16;
    #pragma unroll
    for (int s = 0; s < 5; ++s) {
        float v[16];
        unpack8(*(const uint4*)p, v);
        unpack8(*(const uint4*)(p + 8), v + 8);
        #pragma unroll
        for (int c = 0; c < 16; ++c) acc[c] += fmaxf(v[c] * scl[c] + shf[c], 0.f);
        p += 9216 * 16;
    }
    if (sg > 0) {
        #pragma unroll
        for (int c = 0; c < 16; ++c) part[sg - 1][px][c] = acc[c];
    }
    __syncthreads();
    if (sg == 0) {
        #pragma unroll
        for (int c = 0; c < 16; ++c) acc[c] += part[0][px][c] + part[1][px][c] + part[2][px][c];
        float* o = out + ((size_t)b * 9216 + pix) * 16;
        #pragma unroll
        for (int q = 0; q < 4; ++q)
            *(float4*)(o + 4 * q) = make_float4(acc[4 * q], acc[4 * q + 1], acc[4 * q + 2], acc[4 * q + 3]);
    }
}

// =====================================================================
// pe = 1x1 conv [support; loo] via ONE mfma per 16 pixels + fused per-(s,c)
// stats. 256 px per block (5760 blocks) for latency hiding.
// =====================================================================
__global__ __launch_bounds__(256)
void pe_kernel(const unsigned short* __restrict__ spad, unsigned short* __restrict__ sxpe,
               const float* __restrict__ sxsum, const float* __restrict__ statsSx,
               const float* __restrict__ cgm, const float* __restrict__ cbt,
               const float* __restrict__ pw, const float* __restrict__ pb,
               float* __restrict__ statsPe)
{
    __shared__ float sscl[16], sshf[16];
    __shared__ float red[4][2][16];
    const int tid = threadIdx.x;
    if (tid < 16) bn_coef(statsSx, 16, tid, 1.f / 1474560.f, cgm, cbt, sscl, sshf);
    const int lane = tid & 63, wv = tid >> 6;
    const int p = lane & 15, g = lane >> 4;
    const int img = blockIdx.x / 36;
    const int chunk = blockIdx.x - img * 36;
    const int b = img / 20, s = img - b * 20;
    const int c0 = (g & 1) * 8;

    short8 fw;
    {
        const float4 wa = *(const float4*)(pw + p * 32 + g * 8);
        const float4 wb = *(const float4*)(pw + p * 32 + g * 8 + 4);
        fw[0] = (short)f2bf(wa.x); fw[1] = (short)f2bf(wa.y);
        fw[2] = (short)f2bf(wa.z); fw[3] = (short)f2bf(wa.w);
        fw[4] = (short)f2bf(wb.x); fw[5] = (short)f2bf(wb.y);
        fw[6] = (short)f2bf(wb.z); fw[7] = (short)f2bf(wb.w);
    }
    const float4 b4 = *(const float4*)(pb + 4 * g);
    const float bias[4] = {b4.x, b4.y, b4.z, b4.w};
    __syncthreads();
    float scl[8], shf[8];
    #pragma unroll
    for (int e = 0; e < 8; ++e) { scl[e] = sscl[c0 + e]; shf[e] = sshf[c0 + e]; }

    const unsigned short* imgspad = spad + (size_t)img * 9604 * 16;
    unsigned short* imgsx = sxpe + (size_t)img * 9216 * 16;
    const float* bsum = sxsum + (size_t)b * 9216 * 16;

    float s1[4] = {0.f, 0.f, 0.f, 0.f}, s2[4] = {0.f, 0.f, 0.f, 0.f};

    #pragma unroll
    for (int it = 0; it < 4; ++it) {
        const int pix = chunk * 256 + it * 64 + wv * 16 + p;
        short8 bf;
        if (g < 2) {
            const int row = pix / 96, col = pix - row * 96;
            const int sw = ((col + 1) >> 2) & 1;
            bf = *(const short8*)(imgspad + ((row + 1) * 98 + col + 1) * 16 + (((g ^ sw) & 1) << 3));
        } else {
            float xv[8];
            unpack8(*(const uint4*)(imgsx + (size_t)pix * 16 + c0), xv);
            const float* sm = bsum + (size_t)pix * 16 + c0;
            const float4 sma = *(const float4*)sm;
            const float4 smb = *(const float4*)(sm + 4);
            const float smv[8] = {sma.x, sma.y, sma.z, sma.w, smb.x, smb.y, smb.z, smb.w};
            #pragma unroll
            for (int e = 0; e < 8; ++e) {
                const float loo = smv[e] - fmaxf(xv[e] * scl[e] + shf[e], 0.f);
                bf[e] = (short)f2bf(loo);
            }
        }
        floatx4 acc = {0.f, 0.f, 0.f, 0.f};
        acc = __builtin_amdgcn_mfma_f32_16x16x32_bf16(fw, bf, acc, 0, 0, 0);
        const float v0 = acc[0] + bias[0], v1 = acc[1] + bias[1];
        const float v2 = acc[2] + bias[2], v3 = acc[3] + bias[3];
        s1[0] += v0; s1[1] += v1; s1[2] += v2; s1[3] += v3;
        s2[0] += v0 * v0; s2[1] += v1 * v1; s2[2] += v2 * v2; s2[3] += v3 * v3;
        *(uint2*)(imgsx + (size_t)pix * 16 + 4 * g) =
            make_uint2((unsigned)f2bf(v0) | ((unsigned)f2bf(v1) << 16),
                       (unsigned)f2bf(v2) | ((unsigned)f2bf(v3) << 16));
    }

    #pragma unroll
    for (int r = 0; r < 4; ++r) {
        #pragma unroll
        for (int d = 1; d < 16; d <<= 1) {
            s1[r] += __shfl_xor(s1[r], d);
            s2[r] += __shfl_xor(s2[r], d);
        }
    }
    if (p == 0) {
        #pragma unroll
        for (int r = 0; r < 4; ++r) { red[wv][0][g * 4 + r] = s1[r]; red[wv][1][g * 4 + r] = s2[r]; }
    }
    __syncthreads();
    if (tid < 32) {
        const int st = tid >> 4, c = tid & 15;
        const float v = red[0][st][c] + red[1][st][c] + red[2][st][c] + red[3][st][c];
        atomicAdd(&statsPe[st * 320 + s * 16 + c], v);
    }
}

// ---------------- deep: mean_s relu(bn_{s,c}(pe)), 4-way s split, coef prologue
__global__ __launch_bounds__(256)
void deep_kernel(const unsigned short* __restrict__ pe, const float* __restrict__ statsPe,
                 const float* __restrict__ pg, const float* __restrict__ pbt,
                 unsigned short* __restrict__ deeppad)
{
    __shared__ float scl[320], shf[320];
    __shared__ float part[3][64][17];
    const int tid = threadIdx.x;
    for (int i = tid; i < 320; i += 256)
        bn_coef(statsPe, 320, i, 1.f / 73728.f, pg, pbt, scl, shf);
    const int b = blockIdx.x / 144;
    const int chunk = blockIdx.x - b * 144;
    const int px = tid & 63, sg = tid >> 6;
    const int pix = chunk * 64 + px;
    __syncthreads();
    float acc[16];
    #pragma unroll
    for (int c = 0; c < 16; ++c) acc[c] = 0.f;
    const unsigned short* p = pe + ((size_t)(b * 20 + sg * 5) * 9216 + pix) * 16;
    #pragma unroll
    for (int s = 0; s < 5; ++s) {
        const int si = sg * 5 + s;
        float v[16];
        unpack8(*(const uint4*)p, v);
        unpack8(*(const uint4*)(p + 8), v + 8);
        #pragma unroll
        for (int c = 0; c < 16; ++c) acc[c] += fmaxf(v[c] * scl[si * 16 + c] + shf[si * 16 + c], 0.f);
        p += 9216 * 16;
    }
    if (sg > 0) {
        #pragma unroll
        for (int c = 0; c < 16; ++c) part[sg - 1][px][c] = acc[c];
    }
    __syncthreads();
    if (sg == 0) {
        #pragma unroll
        for (int c = 0; c < 16; ++c)
            acc[c] = (acc[c] + part[0][px][c] + part[1][px][c] + part[2][px][c]) * 0.05f;
        const int row = pix / 96, col = pix - row * 96;
        const int sw = ((col + 1) >> 2) & 1;
        unsigned short* d = deeppad + ((size_t)b * 9604 + (row + 1) * 98 + col + 1) * 16;
        *(uint4*)(d + (sw << 3)) = pack8(acc);
        *(uint4*)(d + ((sw ^ 1) << 3)) = pack8(acc + 8);
    }
}

// ---------------- proj = maxpool2(softmax_ch(bn(conv_j))), coef prologue
__global__ __launch_bounds__(256)
void proj_kernel(const unsigned short* __restrict__ pj, const float* __restrict__ statsJ,
                 const float* __restrict__ jg, const float* __restrict__ jbt,
                 float* __restrict__ proj)
{
    __shared__ float scl[16], shf[16];
    const int tid = threadIdx.x;
    if (tid < 16) bn_coef(statsJ, 16, tid, 1.f / 73728.f, jg, jbt, scl, shf);
    const int b = blockIdx.x / 9;
    const int opix = (blockIdx.x - b * 9) * 256 + tid;
    __syncthreads();
    const int oi = opix / 48, oj = opix - oi * 48;
    float mx[16];
    #pragma unroll
    for (int c = 0; c < 16; ++c) mx[c] = 0.f;
    #pragma unroll
    for (int dy = 0; dy < 2; ++dy) {
        const unsigned short* q = pj + ((size_t)b * 9216 + (2 * oi + dy) * 96 + 2 * oj) * 16;
        #pragma unroll
        for (int dx = 0; dx < 2; ++dx) {
            float v[16]; float mval = -1e30f;
            unpack8(*(const uint4*)(q + dx * 16), v);
            unpack8(*(const uint4*)(q + dx * 16 + 8), v + 8);
            #pragma unroll
            for (int c = 0; c < 16; ++c) { v[c] = v[c] * scl[c] + shf[c]; mval = fmaxf(mval, v[c]); }
            float ssum = 0.f;
            #pragma unroll
            for (int c = 0; c < 16; ++c) { v[c] = __expf(v[c] - mval); ssum += v[c]; }
            const float inv = 1.f / ssum;
            #pragma unroll
            for (int c = 0; c < 16; ++c) mx[c] = fmaxf(mx[c], v[c] * inv);
        }
    }
    float* o = proj + ((size_t)b * 2304 + opix) * 16;
    #pragma unroll
    for (int q2 = 0; q2 < 4; ++q2)
        *(float4*)(o + 4 * q2) = make_float4(mx[4 * q2], mx[4 * q2 + 1], mx[4 * q2 + 2], mx[4 * q2 + 3]);
}

// ---------------- merged outputs: blocks [0,1440) support, [1440,1512) anchor
__global__ __launch_bounds__(256)
void out_kernel(const unsigned short* __restrict__ srp, const unsigned short* __restrict__ axp,
                const float* __restrict__ statsSr, const float* __restrict__ statsAx,
                const float* __restrict__ rg, const float* __restrict__ rbt,
                const float* __restrict__ proj, float* __restrict__ outS,
                float* __restrict__ outA)
{
    __shared__ float scl[16], shf[16];
    const int tid = threadIdx.x;
    const bool sup = blockIdx.x < 1440;
    if (tid < 16) {
        if (sup) bn_coef(statsSr, 16, tid, 1.f / 1474560.f, rg, rbt, scl, shf);
        else     bn_coef(statsAx, 16, tid, 1.f / 73728.f, rg, rbt, scl, shf);
    }
    const int bid = sup ? blockIdx.x : blockIdx.x - 1440;
    const int bs = bid / 9;
    const int opix = (bid - bs * 9) * 256 + tid;
    const int b = sup ? bs / 20 : bs;
    __syncthreads();
    const unsigned short* p = (sup ? srp : axp) + ((size_t)bs * 2304 + opix) * 16;
    float v[16];
    unpack8(*(const uint4*)p, v);
    unpack8(*(const uint4*)(p + 8), v + 8);
    const float* pr = proj + ((size_t)b * 2304 + opix) * 16;
    float* o = sup ? outS : outA;
    #pragma unroll
    for (int c = 0; c < 16; ++c)
        o[((size_t)bs * 16 + c) * 2304 + opix] = fmaxf(v[c] * scl[c] + shf[c], 0.f) * pr[c];
}

extern "C" void kernel_launch(void* const* d_in, const int* in_sizes, int n_in,
                              void* d_out, int out_size, void* d_ws, size_t ws_size,
                              hipStream_t stream)
{
    const float* anchor  = (const float*)d_in[0];
    const float* support = (const float*)d_in[1];
    const float* cw  = (const float*)d_in[2];
    const float* cb  = (const float*)d_in[3];
    const float* cgm = (const float*)d_in[4];
    const float* cbt = (const float*)d_in[5];
    const float* pw  = (const float*)d_in[6];
    const float* pb  = (const float*)d_in[7];
    const float* pg  = (const float*)d_in[8];
    const float* pbt = (const float*)d_in[9];
    const float* jw  = (const float*)d_in[10];
    const float* jb  = (const float*)d_in[11];
    const float* jg  = (const float*)d_in[12];
    const float* jbt = (const float*)d_in[13];
    const float* rw  = (const float*)d_in[14];
    const float* rb  = (const float*)d_in[15];
    const float* rg  = (const float*)d_in[16];
    const float* rbt = (const float*)d_in[17];
    float* out = (float*)d_out;

    char* ws = (char*)d_ws;
    // spad [0, 49.2MB) dead after pe -> pre_j/proj overlay it.
    // apad [49.2MB, 51.6MB) dead after conv_main -> deeppad overlays it.
    unsigned short* spad    = (unsigned short*)ws;
    unsigned short* pre_j   = (unsigned short*)(ws + 2458624);           // overlay (post-pe)
    float*          proj    = (float*)(ws + 4817920);                    // overlay (post-pe)
    unsigned short* apad    = (unsigned short*)(ws + 49172480);          // 2,458,624
    unsigned short* deeppad = apad;                                      // overlay (post conv_main)
    unsigned short* sxpe    = (unsigned short*)(ws + 51631104);          // 47,185,920
    unsigned short* srp     = (unsigned short*)(ws + 98817024);          // 11,796,480
    unsigned short* axp     = (unsigned short*)(ws + 110613504);         // 589,824
    float*          sxsum   = (float*)(ws + 111203328);                  // 4,718,592
    unsigned short* frag    = (unsigned short*)(ws + 115921920);         // 15,360
    float*          stats   = (float*)(ws + 115937280);                  // 3,072

    unsigned short* fragR = frag;
    unsigned short* fragC = frag + 5 * 64 * 8;
    unsigned short* fragJ = frag + 10 * 64 * 8;
    float* statsAx = stats,      *statsSr = stats + 32, *statsSx = stats + 64;
    float* statsPe = stats + 96, *statsJ  = stats + 736;

    pack_kernel<<<6308, 256, 0, stream>>>(support, anchor, spad, apad, rw, cw, jw, frag, stats);
    conv_main_kernel<<<2016, 256, 0, stream>>>(spad, apad, fragR, rb, fragC, cb,
                                               srp, sxpe, axp, statsSr, statsSx, statsAx);
    // apad dead from here: deeppad overlays it (halo zeroed inside sxsum)
    sxsum_kernel<<<1152, 256, 0, stream>>>(sxpe, statsSx, cgm, cbt, sxsum, deeppad);
    pe_kernel<<<5760, 256, 0, stream>>>(spad, sxpe, sxsum, statsSx, cgm, cbt, pw, pb, statsPe);
    // spad dead from here: pre_j / proj overlay it
    deep_kernel<<<1152, 256, 0, stream>>>(sxpe, statsPe, pg, pbt, deeppad);
    conv_j_kernel<<<96, 256, 0, stream>>>(deeppad, fragJ, jb, pre_j, statsJ);
    proj_kernel<<<72, 256, 0, stream>>>(pre_j, statsJ, jg, jbt, proj);
    out_kernel<<<1512, 256, 0, stream>>>(srp, axp, statsSr, statsAx, rg, rbt, proj,
                                         out + 294912, out);
}

// Round 12
// 138.875 us; speedup vs baseline: 1.1840x; 1.0029x over previous
//
#include <hip/hip_runtime.h>
#include <stdint.h>

#define EPS_BN 1e-5f

typedef __attribute__((ext_vector_type(8))) short short8;
typedef __attribute__((ext_vector_type(4))) float floatx4;

__device__ __forceinline__ unsigned short f2bf(float f) {
    unsigned u = __builtin_bit_cast(unsigned, f);
    u += 0x7fffu + ((u >> 16) & 1u);   // RNE
    return (unsigned short)(u >> 16);
}
__device__ __forceinline__ float bf2f(unsigned short h) {
    unsigned u = ((unsigned)h) << 16;
    return __builtin_bit_cast(float, u);
}
__device__ __forceinline__ void unpack8(uint4 q, float* v) {
    v[0] = bf2f((unsigned short)q.x); v[1] = bf2f((unsigned short)(q.x >> 16));
    v[2] = bf2f((unsigned short)q.y); v[3] = bf2f((unsigned short)(q.y >> 16));
    v[4] = bf2f((unsigned short)q.z); v[5] = bf2f((unsigned short)(q.z >> 16));
    v[6] = bf2f((unsigned short)q.w); v[7] = bf2f((unsigned short)(q.w >> 16));
}
__device__ __forceinline__ uint4 pack8(const float* v) {
    uint4 q;
    q.x = (unsigned)f2bf(v[0]) | ((unsigned)f2bf(v[1]) << 16);
    q.y = (unsigned)f2bf(v[2]) | ((unsigned)f2bf(v[3]) << 16);
    q.z = (unsigned)f2bf(v[4]) | ((unsigned)f2bf(v[5]) << 16);
    q.w = (unsigned)f2bf(v[6]) | ((unsigned)f2bf(v[7]) << 16);
    return q;
}

__device__ __forceinline__ void async_copy16(const unsigned short* g, unsigned short* l) {
    __builtin_amdgcn_global_load_lds(
        (const __attribute__((address_space(1))) unsigned int*)(const void*)g,
        (__attribute__((address_space(3))) unsigned int*)(void*)l,
        16, 0, 0);
}

// scale = g*rsqrt(var+eps), shift = b - mean*scale, from raw sum/sumsq
__device__ __forceinline__ void bn_coef(const float* st, int n, int c, float invN,
                                        const float* gg, const float* bb,
                                        float* scl, float* shf) {
    const float mean = st[c] * invN;
    const float var = st[n + c] * invN - mean * mean;
    const float sc = gg[c & 15] * rsqrtf(var + EPS_BN);
    scl[c] = sc;
    shf[c] = bb[c & 15] - mean * sc;
}

// =====================================================================
// pack: fp32 NCHW -> padded (halo-zeroed) bf16 NHWC, ch-half swizzled by
// (paddedcol>>2)&1. Blocks >= 6303 do weight fragments + stats zero.
// =====================================================================
__global__ __launch_bounds__(256)
void pack_kernel(const float* __restrict__ support, const float* __restrict__ anchor,
                 unsigned short* __restrict__ spad, unsigned short* __restrict__ apad,
                 const float* __restrict__ rw, const float* __restrict__ cw,
                 const float* __restrict__ jw, unsigned short* __restrict__ frag,
                 float* __restrict__ stats)
{
    const int tid = threadIdx.x;
    if (blockIdx.x >= 6303) {
        const int bx = blockIdx.x - 6303;
        if (bx == 4) {
            #pragma unroll
            for (int k = 0; k < 3; ++k) stats[k * 256 + tid] = 0.f;
            return;
        }
        const int idx = bx * 256 + tid;
        if (idx >= 960) return;
        const int combo = idx >> 6, lane = idx & 63;
        const int cv = combo / 5, j = combo - cv * 5;
        const float* w = (cv == 0) ? rw : (cv == 1) ? cw : jw;
        const int o = lane & 15, g = lane >> 4;
        unsigned short e8[8];
        #pragma unroll
        for (int e = 0; e < 8; ++e) {
            const int k = j * 32 + g * 8 + e;
            unsigned short val = 0;
            if (k < 144) {
                const int t = k >> 4, i = k & 15;
                const int kh = t / 3, kw = t - kh * 3;
                val = f2bf(w[((o * 16 + i) * 3 + kh) * 3 + kw]);
            }
            e8[e] = val;
        }
        *(uint4*)(frag + ((size_t)combo * 64 + lane) * 8) =
            make_uint4((unsigned)e8[0] | ((unsigned)e8[1] << 16), (unsigned)e8[2] | ((unsigned)e8[3] << 16),
                       (unsigned)e8[4] | ((unsigned)e8[5] << 16), (unsigned)e8[6] | ((unsigned)e8[7] << 16));
        return;
    }
    const int idx = blockIdx.x * 256 + tid;
    if (idx >= 168 * 9604) return;
    const int img = idx / 9604;
    const int rem = idx - img * 9604;
    const int pr = rem / 98, pc = rem - pr * 98;
    const int gh = pr - 1, gw = pc - 1;
    const bool ok = (gh >= 0) & (gh < 96) & (gw >= 0) & (gw < 96);
    const float* src = (img < 160) ? (support + (size_t)img * 147456)
                                   : (anchor + (size_t)(img - 160) * 147456);
    unsigned short* dst = (img < 160) ? (spad + (size_t)img * 9604 * 16)
                                      : (apad + (size_t)(img - 160) * 9604 * 16);
    const int gbase = gh * 96 + gw;
    unsigned pk[8];
    #pragma unroll
    for (int c = 0; c < 8; ++c) {
        const float v0 = ok ? src[(2 * c) * 9216 + gbase] : 0.f;
        const float v1 = ok ? src[(2 * c + 1) * 9216 + gbase] : 0.f;
        pk[c] = (unsigned)f2bf(v0) | ((unsigned)f2bf(v1) << 16);
    }
    const int sw = (pc >> 2) & 1;
    unsigned short* p = dst + (size_t)rem * 16;
    *(uint4*)(p + (sw << 3)) = make_uint4(pk[0], pk[1], pk[2], pk[3]);       // ch 0..7
    *(uint4*)(p + ((sw ^ 1) << 3)) = make_uint4(pk[4], pk[5], pk[6], pk[7]); // ch 8..15
}

// =====================================================================
// conv 3x3 pad1 via MFMA (A=weights 16o x k, B=pixels k x 16pix).
// POOLA templated (2x2 maxpool pre-BN on A output), `two` runtime.
// =====================================================================
template<bool POOLA>
__device__ __forceinline__ void conv_tile(
    unsigned short* lds, float* red,
    const unsigned short* __restrict__ imgin,
    const unsigned short* __restrict__ fragA, const float* __restrict__ bA,
    const unsigned short* __restrict__ fragB, const float* __restrict__ bB,
    unsigned short* __restrict__ outAimg, unsigned short* __restrict__ outBimg,
    float* __restrict__ statsA, float* __restrict__ statsB,
    const int r0b, const bool two)
{
    const int tid = threadIdx.x;
    const int lane = tid & 63;
    const int wv = tid >> 6;

    const unsigned short* gsrc = imgin + (size_t)(r0b * 8 * 98) * 16;
    #pragma unroll
    for (int k = 0; k < 8; ++k) {
        const int chunk = k * 256 + tid;
        if (chunk < 1960)
            async_copy16(gsrc + (size_t)chunk * 8, lds + (k * 256 + wv * 64) * 8);
    }

    const int n = lane & 15, g = lane >> 4;
    short8 fA[5], fB[5];
    #pragma unroll
    for (int j = 0; j < 5; ++j) {
        fA[j] = *(const short8*)(fragA + ((size_t)j * 64 + lane) * 8);
        if (two) fB[j] = *(const short8*)(fragB + ((size_t)j * 64 + lane) * 8);
    }
    const float4 bA4 = *(const float4*)(bA + 4 * g);
    float4 bB4 = make_float4(0.f, 0.f, 0.f, 0.f);
    if (two) bB4 = *(const float4*)(bB + 4 * g);
    const float biasA[4] = {bA4.x, bA4.y, bA4.z, bA4.w};
    const float biasB[4] = {bB4.x, bB4.y, bB4.z, bB4.w};

    __syncthreads();

    float s1A[4] = {0.f, 0.f, 0.f, 0.f}, s2A[4] = {0.f, 0.f, 0.f, 0.f};
    float s1B[4] = {0.f, 0.f, 0.f, 0.f}, s2B[4] = {0.f, 0.f, 0.f, 0.f};

    for (int cg = 0; cg < 6; ++cg) {
        float pA[2][4], pB[2][4];
        #pragma unroll
        for (int tr = 0; tr < 2; ++tr) {
            const int lr = 2 * wv + tr;
            floatx4 aA = {0.f, 0.f, 0.f, 0.f};
            floatx4 aB = {0.f, 0.f, 0.f, 0.f};
            #pragma unroll
            for (int j = 0; j < 5; ++j) {
                const int t = (j < 4) ? (2 * j + (g >> 1)) : 8;
                const int kh = t / 3, kw = t - kh * 3;
                const int ldscol = cg * 16 + n + kw;
                const int half = (g & 1) ^ ((ldscol >> 2) & 1);
                const short8 a = *(const short8*)&lds[((lr + kh) * 98 + ldscol) * 16 + (half << 3)];
                aA = __builtin_amdgcn_mfma_f32_16x16x32_bf16(fA[j], a, aA, 0, 0, 0);
                if (two) aB = __builtin_amdgcn_mfma_f32_16x16x32_bf16(fB[j], a, aB, 0, 0, 0);
            }
            #pragma unroll
            for (int r = 0; r < 4; ++r) {
                const float vA = aA[r] + biasA[r];
                pA[tr][r] = vA; s1A[r] += vA; s2A[r] += vA * vA;
                if (two) {
                    const float vB = aB[r] + biasB[r];
                    pB[tr][r] = vB; s1B[r] += vB; s2B[r] += vB * vB;
                }
            }
            const int grow = r0b * 8 + lr;
            const size_t pixbase = ((size_t)(grow * 96 + cg * 16 + n)) * 16 + 4 * g;
            if (two)
                *(uint2*)(outBimg + pixbase) =
                    make_uint2((unsigned)f2bf(pB[tr][0]) | ((unsigned)f2bf(pB[tr][1]) << 16),
                               (unsigned)f2bf(pB[tr][2]) | ((unsigned)f2bf(pB[tr][3]) << 16));
            if (!POOLA)
                *(uint2*)(outAimg + pixbase) =
                    make_uint2((unsigned)f2bf(pA[tr][0]) | ((unsigned)f2bf(pA[tr][1]) << 16),
                               (unsigned)f2bf(pA[tr][2]) | ((unsigned)f2bf(pA[tr][3]) << 16));
        }
        if (POOLA) {
            float pm[4];
            #pragma unroll
            for (int r = 0; r < 4; ++r) {
                pm[r] = fmaxf(pA[0][r], pA[1][r]);
                pm[r] = fmaxf(pm[r], __shfl_xor(pm[r], 1));
            }
            if (!(n & 1)) {
                const int orow = r0b * 4 + wv;
                const size_t ob = ((size_t)(orow * 48 + cg * 8 + (n >> 1))) * 16 + 4 * g;
                *(uint2*)(outAimg + ob) =
                    make_uint2((unsigned)f2bf(pm[0]) | ((unsigned)f2bf(pm[1]) << 16),
                               (unsigned)f2bf(pm[2]) | ((unsigned)f2bf(pm[3]) << 16));
            }
        }
    }

    #pragma unroll
    for (int r = 0; r < 4; ++r) {
        #pragma unroll
        for (int d = 1; d < 16; d <<= 1) {
            s1A[r] += __shfl_xor(s1A[r], d); s2A[r] += __shfl_xor(s2A[r], d);
            if (two) { s1B[r] += __shfl_xor(s1B[r], d); s2B[r] += __shfl_xor(s2B[r], d); }
        }
    }
    if (n == 0) {
        #pragma unroll
        for (int r = 0; r < 4; ++r) {
            red[(wv * 4 + 0) * 16 + g * 4 + r] = s1A[r];
            red[(wv * 4 + 1) * 16 + g * 4 + r] = s2A[r];
            if (two) {
                red[(wv * 4 + 2) * 16 + g * 4 + r] = s1B[r];
                red[(wv * 4 + 3) * 16 + g * 4 + r] = s2B[r];
            }
        }
    }
    __syncthreads();
    if (tid < (two ? 64 : 32)) {
        const int st = tid >> 4, oc = tid & 15;
        const float v = red[(0 * 4 + st) * 16 + oc] + red[(1 * 4 + st) * 16 + oc] +
                        red[(2 * 4 + st) * 16 + oc] + red[(3 * 4 + st) * 16 + oc];
        float* dst = (st < 2) ? statsA : statsB;
        atomicAdd(&dst[(st & 1) * 16 + oc], v);
    }
}

// main conv: logical blocks [0,1920) = support (dual conv), [1920,2016) = anchor.
// XCD-bijective swizzle (2016 = 8*252): consecutive strips (shared halo rows
// + weight frags) co-reside on one XCD L2.
__global__ __launch_bounds__(256, 4)
void conv_main_kernel(const unsigned short* __restrict__ spad, const unsigned short* __restrict__ apad,
                      const unsigned short* __restrict__ fragR, const float* __restrict__ rb,
                      const unsigned short* __restrict__ fragC, const float* __restrict__ cb,
                      unsigned short* __restrict__ srp, unsigned short* __restrict__ sxpe,
                      unsigned short* __restrict__ axp,
                      float* __restrict__ statsSr, float* __restrict__ statsSx,
                      float* __restrict__ statsAx)
{
    __shared__ __align__(16) unsigned short lds[10 * 98 * 16];
    __shared__ float red[4 * 4 * 16];
    const int bid0 = (blockIdx.x & 7) * 252 + (blockIdx.x >> 3);
    const bool two = bid0 < 1920;
    const int bid = two ? bid0 : bid0 - 1920;
    const int img = bid / 12;
    const int r0b = bid - img * 12;
    const unsigned short* in = (two ? spad : apad) + (size_t)img * 9604 * 16;
    unsigned short* outA = (two ? srp : axp) + (size_t)img * 2304 * 16;
    unsigned short* outB = sxpe + (size_t)img * 9216 * 16;
    conv_tile<true>(lds, red, in, fragR, rb, fragC, cb, outA, outB,
                    two ? statsSr : statsAx, statsSx, r0b, two);
}

// projector conv (deep -> pre_j, unpooled); XCD swizzle (96 = 8*12)
__global__ __launch_bounds__(256, 4)
void conv_j_kernel(const unsigned short* __restrict__ deeppad,
                   const unsigned short* __restrict__ fragJ, const float* __restrict__ jb,
                   unsigned short* __restrict__ pre_j, float* __restrict__ statsJ)
{
    __shared__ __align__(16) unsigned short lds[10 * 98 * 16];
    __shared__ float red[4 * 4 * 16];
    const int bid0 = (blockIdx.x & 7) * 12 + (blockIdx.x >> 3);
    const int img = bid0 / 12;
    const int r0b = bid0 - img * 12;
    conv_tile<false>(lds, red, deeppad + (size_t)img * 9604 * 16, fragJ, jb, nullptr, nullptr,
                     pre_j + (size_t)img * 9216 * 16, nullptr, statsJ, nullptr, r0b, false);
}

// ---------------- sxsum[b][pix][c] = sum_s relu(bn(sx)); 5-way s split
// (320 threads: sg=tid>>6 in [0,5), 4 s each); blocks 0..9 also zero the
// deeppad halo ring
__global__ __launch_bounds__(320)
void sxsum_kernel(const unsigned short* __restrict__ sx, const float* __restrict__ statsSx,
                  const float* __restrict__ cgm, const float* __restrict__ cbt,
                  float* __restrict__ out, unsigned short* __restrict__ deeppad)
{
    __shared__ float scl[16], shf[16];
    __shared__ float part[4][64][17];
    const int tid = threadIdx.x;
    if (blockIdx.x < 10) {
        const int idx = blockIdx.x * 320 + tid;
        if (idx < 8 * 388) {
            const int img = idx / 388;
            const int h = idx - img * 388;
            int pr, pc;
            if (h < 98)       { pr = 0;           pc = h; }
            else if (h < 196) { pr = 97;          pc = h - 98; }
            else if (h < 292) { pr = h - 196 + 1; pc = 0; }
            else              { pr = h - 292 + 1; pc = 97; }
            unsigned short* p = deeppad + ((size_t)img * 9604 + pr * 98 + pc) * 16;
            *(uint4*)p = make_uint4(0, 0, 0, 0);
            *(uint4*)(p + 8) = make_uint4(0, 0, 0, 0);
        }
    }
    if (tid < 16) bn_coef(statsSx, 16, tid, 1.f / 1474560.f, cgm, cbt, scl, shf);
    const int b = blockIdx.x / 144;
    const int chunk = blockIdx.x - b * 144;
    const int px = tid & 63, sg = tid >> 6;   // sg 0..4
    const int pix = chunk * 64 + px;
    __syncthreads();
    float acc[16];
    #pragma unroll
    for (int c = 0; c < 16; ++c) acc[c] = 0.f;
    const unsigned short* p = sx + ((size_t)(b * 20 + sg * 4) * 9216 + pix) * 16;
    #pragma unroll
    for (int s = 0; s < 4; ++s) {
        float v[16];
        unpack8(*(const uint4*)p, v);
        unpack8(*(const uint4*)(p + 8), v + 8);
        #pragma unroll
        for (int c = 0; c < 16; ++c) acc[c] += fmaxf(v[c] * scl[c] + shf[c], 0.f);
        p += 9216 * 16;
    }
    if (sg > 0) {
        #pragma unroll
        for (int c = 0; c < 16; ++c) part[sg - 1][px][c] = acc[c];
    }
    __syncthreads();
    if (sg == 0) {
        #pragma unroll
        for (int c = 0; c < 16; ++c)
            acc[c] += (part[0][px][c] + part[1][px][c]) + (part[2][px][c] + part[3][px][c]);
        float* o = out + ((size_t)b * 9216 + pix) * 16;
        #pragma unroll
        for (int q = 0; q < 4; ++q)
            *(float4*)(o + 4 * q) = make_float4(acc[4 * q], acc[4 * q + 1], acc[4 * q + 2], acc[4 * q + 3]);
    }
}

// =====================================================================
// pe = 1x1 conv [support; loo] via ONE mfma per 16 pixels + fused per-(s,c)
// stats. 256 px per block (5760 blocks) for latency hiding.
// =====================================================================
__global__ __launch_bounds__(256)
void pe_kernel(const unsigned short* __restrict__ spad, unsigned short* __restrict__ sxpe,
               const float* __restrict__ sxsum, const float* __restrict__ statsSx,
               const float* __restrict__ cgm, const float* __restrict__ cbt,
               const float* __restrict__ pw, const float* __restrict__ pb,
               float* __restrict__ statsPe)
{
    __shared__ float sscl[16], sshf[16];
    __shared__ float red[4][2][16];
    const int tid = threadIdx.x;
    if (tid < 16) bn_coef(statsSx, 16, tid, 1.f / 1474560.f, cgm, cbt, sscl, sshf);
    const int lane = tid & 63, wv = tid >> 6;
    const int p = lane & 15, g = lane >> 4;
    const int img = blockIdx.x / 36;
    const int chunk = blockIdx.x - img * 36;
    const int b = img / 20, s = img - b * 20;
    const int c0 = (g & 1) * 8;

    short8 fw;
    {
        const float4 wa = *(const float4*)(pw + p * 32 + g * 8);
        const float4 wb = *(const float4*)(pw + p * 32 + g * 8 + 4);
        fw[0] = (short)f2bf(wa.x); fw[1] = (short)f2bf(wa.y);
        fw[2] = (short)f2bf(wa.z); fw[3] = (short)f2bf(wa.w);
        fw[4] = (short)f2bf(wb.x); fw[5] = (short)f2bf(wb.y);
        fw[6] = (short)f2bf(wb.z); fw[7] = (short)f2bf(wb.w);
    }
    const float4 b4 = *(const float4*)(pb + 4 * g);
    const float bias[4] = {b4.x, b4.y, b4.z, b4.w};
    __syncthreads();
    float scl[8], shf[8];
    #pragma unroll
    for (int e = 0; e < 8; ++e) { scl[e] = sscl[c0 + e]; shf[e] = sshf[c0 + e]; }

    const unsigned short* imgspad = spad + (size_t)img * 9604 * 16;
    unsigned short* imgsx = sxpe + (size_t)img * 9216 * 16;
    const float* bsum = sxsum + (size_t)b * 9216 * 16;

    float s1[4] = {0.f, 0.f, 0.f, 0.f}, s2[4] = {0.f, 0.f, 0.f, 0.f};

    #pragma unroll
    for (int it = 0; it < 4; ++it) {
        const int pix = chunk * 256 + it * 64 + wv * 16 + p;
        short8 bf;
        if (g < 2) {
            const int row = pix / 96, col = pix - row * 96;
            const int sw = ((col + 1) >> 2) & 1;
            bf = *(const short8*)(imgspad + ((row + 1) * 98 + col + 1) * 16 + (((g ^ sw) & 1) << 3));
        } else {
            float xv[8];
            unpack8(*(const uint4*)(imgsx + (size_t)pix * 16 + c0), xv);
            const float* sm = bsum + (size_t)pix * 16 + c0;
            const float4 sma = *(const float4*)sm;
            const float4 smb = *(const float4*)(sm + 4);
            const float smv[8] = {sma.x, sma.y, sma.z, sma.w, smb.x, smb.y, smb.z, smb.w};
            #pragma unroll
            for (int e = 0; e < 8; ++e) {
                const float loo = smv[e] - fmaxf(xv[e] * scl[e] + shf[e], 0.f);
                bf[e] = (short)f2bf(loo);
            }
        }
        floatx4 acc = {0.f, 0.f, 0.f, 0.f};
        acc = __builtin_amdgcn_mfma_f32_16x16x32_bf16(fw, bf, acc, 0, 0, 0);
        const float v0 = acc[0] + bias[0], v1 = acc[1] + bias[1];
        const float v2 = acc[2] + bias[2], v3 = acc[3] + bias[3];
        s1[0] += v0; s1[1] += v1; s1[2] += v2; s1[3] += v3;
        s2[0] += v0 * v0; s2[1] += v1 * v1; s2[2] += v2 * v2; s2[3] += v3 * v3;
        *(uint2*)(imgsx + (size_t)pix * 16 + 4 * g) =
            make_uint2((unsigned)f2bf(v0) | ((unsigned)f2bf(v1) << 16),
                       (unsigned)f2bf(v2) | ((unsigned)f2bf(v3) << 16));
    }

    #pragma unroll
    for (int r = 0; r < 4; ++r) {
        #pragma unroll
        for (int d = 1; d < 16; d <<= 1) {
            s1[r] += __shfl_xor(s1[r], d);
            s2[r] += __shfl_xor(s2[r], d);
        }
    }
    if (p == 0) {
        #pragma unroll
        for (int r = 0; r < 4; ++r) { red[wv][0][g * 4 + r] = s1[r]; red[wv][1][g * 4 + r] = s2[r]; }
    }
    __syncthreads();
    if (tid < 32) {
        const int st = tid >> 4, c = tid & 15;
        const float v = red[0][st][c] + red[1][st][c] + red[2][st][c] + red[3][st][c];
        atomicAdd(&statsPe[st * 320 + s * 16 + c], v);
    }
}

// ---------------- deep: mean_s relu(bn_{s,c}(pe)), 5-way s split (320 thr)
__global__ __launch_bounds__(320)
void deep_kernel(const unsigned short* __restrict__ pe, const float* __restrict__ statsPe,
                 const float* __restrict__ pg, const float* __restrict__ pbt,
                 unsigned short* __restrict__ deeppad)
{
    __shared__ float scl[320], shf[320];
    __shared__ float part[4][64][17];
    const int tid = threadIdx.x;
    bn_coef(statsPe, 320, tid, 1.f / 73728.f, pg, pbt, scl, shf);   // 320 threads = 320 coefs
    const int b = blockIdx.x / 144;
    const int chunk = blockIdx.x - b * 144;
    const int px = tid & 63, sg = tid >> 6;   // sg 0..4
    const int pix = chunk * 64 + px;
    __syncthreads();
    float acc[16];
    #pragma unroll
    for (int c = 0; c < 16; ++c) acc[c] = 0.f;
    const unsigned short* p = pe + ((size_t)(b * 20 + sg * 4) * 9216 + pix) * 16;
    #pragma unroll
    for (int s = 0; s < 4; ++s) {
        const int si = sg * 4 + s;
        float v[16];
        unpack8(*(const uint4*)p, v);
        unpack8(*(const uint4*)(p + 8), v + 8);
        #pragma unroll
        for (int c = 0; c < 16; ++c) acc[c] += fmaxf(v[c] * scl[si * 16 + c] + shf[si * 16 + c], 0.f);
        p += 9216 * 16;
    }
    if (sg > 0) {
        #pragma unroll
        for (int c = 0; c < 16; ++c) part[sg - 1][px][c] = acc[c];
    }
    __syncthreads();
    if (sg == 0) {
        #pragma unroll
        for (int c = 0; c < 16; ++c)
            acc[c] = (acc[c] + (part[0][px][c] + part[1][px][c]) + (part[2][px][c] + part[3][px][c])) * 0.05f;
        const int row = pix / 96, col = pix - row * 96;
        const int sw = ((col + 1) >> 2) & 1;
        unsigned short* d = deeppad + ((size_t)b * 9604 + (row + 1) * 98 + col + 1) * 16;
        *(uint4*)(d + (sw << 3)) = pack8(acc);
        *(uint4*)(d + ((sw ^ 1) << 3)) = pack8(acc + 8);
    }
}

// ---------------- proj = maxpool2(softmax_ch(bn(conv_j))), coef prologue
__global__ __launch_bounds__(256)
void proj_kernel(const unsigned short* __restrict__ pj, const float* __restrict__ statsJ,
                 const float* __restrict__ jg, const float* __restrict__ jbt,
                 float* __restrict__ proj)
{
    __shared__ float scl[16], shf[16];
    const int tid = threadIdx.x;
    if (tid < 16) bn_coef(statsJ, 16, tid, 1.f / 73728.f, jg, jbt, scl, shf);
    const int b = blockIdx.x / 9;
    const int opix = (blockIdx.x - b * 9) * 256 + tid;
    __syncthreads();
    const int oi = opix / 48, oj = opix - oi * 48;
    float mx[16];
    #pragma unroll
    for (int c = 0; c < 16; ++c) mx[c] = 0.f;
    #pragma unroll
    for (int dy = 0; dy < 2; ++dy) {
        const unsigned short* q = pj + ((size_t)b * 9216 + (2 * oi + dy) * 96 + 2 * oj) * 16;
        #pragma unroll
        for (int dx = 0; dx < 2; ++dx) {
            float v[16]; float mval = -1e30f;
            unpack8(*(const uint4*)(q + dx * 16), v);
            unpack8(*(const uint4*)(q + dx * 16 + 8), v + 8);
            #pragma unroll
            for (int c = 0; c < 16; ++c) { v[c] = v[c] * scl[c] + shf[c]; mval = fmaxf(mval, v[c]); }
            float ssum = 0.f;
            #pragma unroll
            for (int c = 0; c < 16; ++c) { v[c] = __expf(v[c] - mval); ssum += v[c]; }
            const float inv = 1.f / ssum;
            #pragma unroll
            for (int c = 0; c < 16; ++c) mx[c] = fmaxf(mx[c], v[c] * inv);
        }
    }
    float* o = proj + ((size_t)b * 2304 + opix) * 16;
    #pragma unroll
    for (int q2 = 0; q2 < 4; ++q2)
        *(float4*)(o + 4 * q2) = make_float4(mx[4 * q2], mx[4 * q2 + 1], mx[4 * q2 + 2], mx[4 * q2 + 3]);
}

// ---------------- merged outputs: blocks [0,1440) support, [1440,1512) anchor
__global__ __launch_bounds__(256)
void out_kernel(const unsigned short* __restrict__ srp, const unsigned short* __restrict__ axp,
                const float* __restrict__ statsSr, const float* __restrict__ statsAx,
                const float* __restrict__ rg, const float* __restrict__ rbt,
                const float* __restrict__ proj, float* __restrict__ outS,
                float* __restrict__ outA)
{
    __shared__ float scl[16], shf[16];
    const int tid = threadIdx.x;
    const bool sup = blockIdx.x < 1440;
    if (tid < 16) {
        if (sup) bn_coef(statsSr, 16, tid, 1.f / 1474560.f, rg, rbt, scl, shf);
        else     bn_coef(statsAx, 16, tid, 1.f / 73728.f, rg, rbt, scl, shf);
    }
    const int bid = sup ? blockIdx.x : blockIdx.x - 1440;
    const int bs = bid / 9;
    const int opix = (bid - bs * 9) * 256 + tid;
    const int b = sup ? bs / 20 : bs;
    __syncthreads();
    const unsigned short* p = (sup ? srp : axp) + ((size_t)bs * 2304 + opix) * 16;
    float v[16];
    unpack8(*(const uint4*)p, v);
    unpack8(*(const uint4*)(p + 8), v + 8);
    const float* pr = proj + ((size_t)b * 2304 + opix) * 16;
    float* o = sup ? outS : outA;
    #pragma unroll
    for (int c = 0; c < 16; ++c)
        o[((size_t)bs * 16 + c) * 2304 + opix] = fmaxf(v[c] * scl[c] + shf[c], 0.f) * pr[c];
}

extern "C" void kernel_launch(void* const* d_in, const int* in_sizes, int n_in,
                              void* d_out, int out_size, void* d_ws, size_t ws_size,
                              hipStream_t stream)
{
    const float* anchor  = (const float*)d_in[0];
    const float* support = (const float*)d_in[1];
    const float* cw  = (const float*)d_in[2];
    const float* cb  = (const float*)d_in[3];
    const float* cgm = (const float*)d_in[4];
    const float* cbt = (const float*)d_in[5];
    const float* pw  = (const float*)d_in[6];
    const float* pb  = (const float*)d_in[7];
    const float* pg  = (const float*)d_in[8];
    const float* pbt = (const float*)d_in[9];
    const float* jw  = (const float*)d_in[10];
    const float* jb  = (const float*)d_in[11];
    const float* jg  = (const float*)d_in[12];
    const float* jbt = (const float*)d_in[13];
    const float* rw  = (const float*)d_in[14];
    const float* rb  = (const float*)d_in[15];
    const float* rg  = (const float*)d_in[16];
    const float* rbt = (const float*)d_in[17];
    float* out = (float*)d_out;

    char* ws = (char*)d_ws;
    // spad [0, 49.2MB) dead after pe -> pre_j/proj overlay it.
    // apad [49.2MB, 51.6MB) dead after conv_main -> deeppad overlays it.
    unsigned short* spad    = (unsigned short*)ws;
    unsigned short* pre_j   = (unsigned short*)(ws + 2458624);           // overlay (post-pe)
    float*          proj    = (float*)(ws + 4817920);                    // overlay (post-pe)
    unsigned short* apad    = (unsigned short*)(ws + 49172480);          // 2,458,624
    unsigned short* deeppad = apad;                                      // overlay (post conv_main)
    unsigned short* sxpe    = (unsigned short*)(ws + 51631104);          // 47,185,920
    unsigned short* srp     = (unsigned short*)(ws + 98817024);          // 11,796,480
    unsigned short* axp     = (unsigned short*)(ws + 110613504);         // 589,824
    float*          sxsum   = (float*)(ws + 111203328);                  // 4,718,592
    unsigned short* frag    = (unsigned short*)(ws + 115921920);         // 15,360
    float*          stats   = (float*)(ws + 115937280);                  // 3,072

    unsigned short* fragR = frag;
    unsigned short* fragC = frag + 5 * 64 * 8;
    unsigned short* fragJ = frag + 10 * 64 * 8;
    float* statsAx = stats,      *statsSr = stats + 32, *statsSx = stats + 64;
    float* statsPe = stats + 96, *statsJ  = stats + 736;

    pack_kernel<<<6308, 256, 0, stream>>>(support, anchor, spad, apad, rw, cw, jw, frag, stats);
    conv_main_kernel<<<2016, 256, 0, stream>>>(spad, apad, fragR, rb, fragC, cb,
                                               srp, sxpe, axp, statsSr, statsSx, statsAx);
    // apad dead from here: deeppad overlays it (halo zeroed inside sxsum)
    sxsum_kernel<<<1152, 320, 0, stream>>>(sxpe, statsSx, cgm, cbt, sxsum, deeppad);
    pe_kernel<<<5760, 256, 0, stream>>>(spad, sxpe, sxsum, statsSx, cgm, cbt, pw, pb, statsPe);
    // spad dead from here: pre_j / proj overlay it
    deep_kernel<<<1152, 320, 0, stream>>>(sxpe, statsPe, pg, pbt, deeppad);
    conv_j_kernel<<<96, 256, 0, stream>>>(deeppad, fragJ, jb, pre_j, statsJ);
    proj_kernel<<<72, 256, 0, stream>>>(pre_j, statsJ, jg, jbt, proj);
    out_kernel<<<1512, 256, 0, stream>>>(srp, axp, statsSr, statsAx, rg, rbt, proj,
                                         out + 294912, out);
}

// Round 13
// 136.381 us; speedup vs baseline: 1.2056x; 1.0183x over previous
//
#include <hip/hip_runtime.h>
#include <stdint.h>

#define EPS_BN 1e-5f

typedef __attribute__((ext_vector_type(8))) short short8;
typedef __attribute__((ext_vector_type(4))) float floatx4;

__device__ __forceinline__ unsigned short f2bf(float f) {
    unsigned u = __builtin_bit_cast(unsigned, f);
    u += 0x7fffu + ((u >> 16) & 1u);   // RNE
    return (unsigned short)(u >> 16);
}
__device__ __forceinline__ float bf2f(unsigned short h) {
    unsigned u = ((unsigned)h) << 16;
    return __builtin_bit_cast(float, u);
}
__device__ __forceinline__ void unpack8(uint4 q, float* v) {
    v[0] = bf2f((unsigned short)q.x); v[1] = bf2f((unsigned short)(q.x >> 16));
    v[2] = bf2f((unsigned short)q.y); v[3] = bf2f((unsigned short)(q.y >> 16));
    v[4] = bf2f((unsigned short)q.z); v[5] = bf2f((unsigned short)(q.z >> 16));
    v[6] = bf2f((unsigned short)q.w); v[7] = bf2f((unsigned short)(q.w >> 16));
}
__device__ __forceinline__ uint4 pack8(const float* v) {
    uint4 q;
    q.x = (unsigned)f2bf(v[0]) | ((unsigned)f2bf(v[1]) << 16);
    q.y = (unsigned)f2bf(v[2]) | ((unsigned)f2bf(v[3]) << 16);
    q.z = (unsigned)f2bf(v[4]) | ((unsigned)f2bf(v[5]) << 16);
    q.w = (unsigned)f2bf(v[6]) | ((unsigned)f2bf(v[7]) << 16);
    return q;
}

__device__ __forceinline__ void async_copy16(const unsigned short* g, unsigned short* l) {
    __builtin_amdgcn_global_load_lds(
        (const __attribute__((address_space(1))) unsigned int*)(const void*)g,
        (__attribute__((address_space(3))) unsigned int*)(void*)l,
        16, 0, 0);
}

// scale = g*rsqrt(var+eps), shift = b - mean*scale, from raw sum/sumsq
__device__ __forceinline__ void bn_coef(const float* st, int n, int c, float invN,
                                        const float* gg, const float* bb,
                                        float* scl, float* shf) {
    const float mean = st[c] * invN;
    const float var = st[n + c] * invN - mean * mean;
    const float sc = gg[c & 15] * rsqrtf(var + EPS_BN);
    scl[c] = sc;
    shf[c] = bb[c & 15] - mean * sc;
}

// =====================================================================
// pack: fp32 NCHW -> padded (halo-zeroed) bf16 NHWC, ch-half swizzled by
// (paddedcol>>2)&1. Blocks >= 6303 do weight fragments + stats zero.
// =====================================================================
__global__ __launch_bounds__(256)
void pack_kernel(const float* __restrict__ support, const float* __restrict__ anchor,
                 unsigned short* __restrict__ spad, unsigned short* __restrict__ apad,
                 const float* __restrict__ rw, const float* __restrict__ cw,
                 const float* __restrict__ jw, unsigned short* __restrict__ frag,
                 float* __restrict__ stats)
{
    const int tid = threadIdx.x;
    if (blockIdx.x >= 6303) {
        const int bx = blockIdx.x - 6303;
        if (bx == 4) {
            #pragma unroll
            for (int k = 0; k < 3; ++k) stats[k * 256 + tid] = 0.f;
            return;
        }
        const int idx = bx * 256 + tid;
        if (idx >= 960) return;
        const int combo = idx >> 6, lane = idx & 63;
        const int cv = combo / 5, j = combo - cv * 5;
        const float* w = (cv == 0) ? rw : (cv == 1) ? cw : jw;
        const int o = lane & 15, g = lane >> 4;
        unsigned short e8[8];
        #pragma unroll
        for (int e = 0; e < 8; ++e) {
            const int k = j * 32 + g * 8 + e;
            unsigned short val = 0;
            if (k < 144) {
                const int t = k >> 4, i = k & 15;
                const int kh = t / 3, kw = t - kh * 3;
                val = f2bf(w[((o * 16 + i) * 3 + kh) * 3 + kw]);
            }
            e8[e] = val;
        }
        *(uint4*)(frag + ((size_t)combo * 64 + lane) * 8) =
            make_uint4((unsigned)e8[0] | ((unsigned)e8[1] << 16), (unsigned)e8[2] | ((unsigned)e8[3] << 16),
                       (unsigned)e8[4] | ((unsigned)e8[5] << 16), (unsigned)e8[6] | ((unsigned)e8[7] << 16));
        return;
    }
    const int idx = blockIdx.x * 256 + tid;
    if (idx >= 168 * 9604) return;
    const int img = idx / 9604;
    const int rem = idx - img * 9604;
    const int pr = rem / 98, pc = rem - pr * 98;
    const int gh = pr - 1, gw = pc - 1;
    const bool ok = (gh >= 0) & (gh < 96) & (gw >= 0) & (gw < 96);
    const float* src = (img < 160) ? (support + (size_t)img * 147456)
                                   : (anchor + (size_t)(img - 160) * 147456);
    unsigned short* dst = (img < 160) ? (spad + (size_t)img * 9604 * 16)
                                      : (apad + (size_t)(img - 160) * 9604 * 16);
    const int gbase = gh * 96 + gw;
    unsigned pk[8];
    #pragma unroll
    for (int c = 0; c < 8; ++c) {
        const float v0 = ok ? src[(2 * c) * 9216 + gbase] : 0.f;
        const float v1 = ok ? src[(2 * c + 1) * 9216 + gbase] : 0.f;
        pk[c] = (unsigned)f2bf(v0) | ((unsigned)f2bf(v1) << 16);
    }
    const int sw = (pc >> 2) & 1;
    unsigned short* p = dst + (size_t)rem * 16;
    *(uint4*)(p + (sw << 3)) = make_uint4(pk[0], pk[1], pk[2], pk[3]);       // ch 0..7
    *(uint4*)(p + ((sw ^ 1) << 3)) = make_uint4(pk[4], pk[5], pk[6], pk[7]); // ch 8..15
}

// =====================================================================
// conv 3x3 pad1 via MFMA (A=weights 16o x k, B=pixels k x 16pix).
// POOLA templated (2x2 maxpool pre-BN on A output), `two` runtime.
// =====================================================================
template<bool POOLA>
__device__ __forceinline__ void conv_tile(
    unsigned short* lds, float* red,
    const unsigned short* __restrict__ imgin,
    const unsigned short* __restrict__ fragA, const float* __restrict__ bA,
    const unsigned short* __restrict__ fragB, const float* __restrict__ bB,
    unsigned short* __restrict__ outAimg, unsigned short* __restrict__ outBimg,
    float* __restrict__ statsA, float* __restrict__ statsB,
    const int r0b, const bool two)
{
    const int tid = threadIdx.x;
    const int lane = tid & 63;
    const int wv = tid >> 6;

    const unsigned short* gsrc = imgin + (size_t)(r0b * 8 * 98) * 16;
    #pragma unroll
    for (int k = 0; k < 8; ++k) {
        const int chunk = k * 256 + tid;
        if (chunk < 1960)
            async_copy16(gsrc + (size_t)chunk * 8, lds + (k * 256 + wv * 64) * 8);
    }

    const int n = lane & 15, g = lane >> 4;
    short8 fA[5], fB[5];
    #pragma unroll
    for (int j = 0; j < 5; ++j) {
        fA[j] = *(const short8*)(fragA + ((size_t)j * 64 + lane) * 8);
        if (two) fB[j] = *(const short8*)(fragB + ((size_t)j * 64 + lane) * 8);
    }
    const float4 bA4 = *(const float4*)(bA + 4 * g);
    float4 bB4 = make_float4(0.f, 0.f, 0.f, 0.f);
    if (two) bB4 = *(const float4*)(bB + 4 * g);
    const float biasA[4] = {bA4.x, bA4.y, bA4.z, bA4.w};
    const float biasB[4] = {bB4.x, bB4.y, bB4.z, bB4.w};

    __syncthreads();

    float s1A[4] = {0.f, 0.f, 0.f, 0.f}, s2A[4] = {0.f, 0.f, 0.f, 0.f};
    float s1B[4] = {0.f, 0.f, 0.f, 0.f}, s2B[4] = {0.f, 0.f, 0.f, 0.f};

    for (int cg = 0; cg < 6; ++cg) {
        float pA[2][4], pB[2][4];
        #pragma unroll
        for (int tr = 0; tr < 2; ++tr) {
            const int lr = 2 * wv + tr;
            floatx4 aA = {0.f, 0.f, 0.f, 0.f};
            floatx4 aB = {0.f, 0.f, 0.f, 0.f};
            #pragma unroll
            for (int j = 0; j < 5; ++j) {
                const int t = (j < 4) ? (2 * j + (g >> 1)) : 8;
                const int kh = t / 3, kw = t - kh * 3;
                const int ldscol = cg * 16 + n + kw;
                const int half = (g & 1) ^ ((ldscol >> 2) & 1);
                const short8 a = *(const short8*)&lds[((lr + kh) * 98 + ldscol) * 16 + (half << 3)];
                aA = __builtin_amdgcn_mfma_f32_16x16x32_bf16(fA[j], a, aA, 0, 0, 0);
                if (two) aB = __builtin_amdgcn_mfma_f32_16x16x32_bf16(fB[j], a, aB, 0, 0, 0);
            }
            #pragma unroll
            for (int r = 0; r < 4; ++r) {
                const float vA = aA[r] + biasA[r];
                pA[tr][r] = vA; s1A[r] += vA; s2A[r] += vA * vA;
                if (two) {
                    const float vB = aB[r] + biasB[r];
                    pB[tr][r] = vB; s1B[r] += vB; s2B[r] += vB * vB;
                }
            }
            const int grow = r0b * 8 + lr;
            const size_t pixbase = ((size_t)(grow * 96 + cg * 16 + n)) * 16 + 4 * g;
            if (two)
                *(uint2*)(outBimg + pixbase) =
                    make_uint2((unsigned)f2bf(pB[tr][0]) | ((unsigned)f2bf(pB[tr][1]) << 16),
                               (unsigned)f2bf(pB[tr][2]) | ((unsigned)f2bf(pB[tr][3]) << 16));
            if (!POOLA)
                *(uint2*)(outAimg + pixbase) =
                    make_uint2((unsigned)f2bf(pA[tr][0]) | ((unsigned)f2bf(pA[tr][1]) << 16),
                               (unsigned)f2bf(pA[tr][2]) | ((unsigned)f2bf(pA[tr][3]) << 16));
        }
        if (POOLA) {
            float pm[4];
            #pragma unroll
            for (int r = 0; r < 4; ++r) {
                pm[r] = fmaxf(pA[0][r], pA[1][r]);
                pm[r] = fmaxf(pm[r], __shfl_xor(pm[r], 1));
            }
            if (!(n & 1)) {
                const int orow = r0b * 4 + wv;
                const size_t ob = ((size_t)(orow * 48 + cg * 8 + (n >> 1))) * 16 + 4 * g;
                *(uint2*)(outAimg + ob) =
                    make_uint2((unsigned)f2bf(pm[0]) | ((unsigned)f2bf(pm[1]) << 16),
                               (unsigned)f2bf(pm[2]) | ((unsigned)f2bf(pm[3]) << 16));
            }
        }
    }

    #pragma unroll
    for (int r = 0; r < 4; ++r) {
        #pragma unroll
        for (int d = 1; d < 16; d <<= 1) {
            s1A[r] += __shfl_xor(s1A[r], d); s2A[r] += __shfl_xor(s2A[r], d);
            if (two) { s1B[r] += __shfl_xor(s1B[r], d); s2B[r] += __shfl_xor(s2B[r], d); }
        }
    }
    if (n == 0) {
        #pragma unroll
        for (int r = 0; r < 4; ++r) {
            red[(wv * 4 + 0) * 16 + g * 4 + r] = s1A[r];
            red[(wv * 4 + 1) * 16 + g * 4 + r] = s2A[r];
            if (two) {
                red[(wv * 4 + 2) * 16 + g * 4 + r] = s1B[r];
                red[(wv * 4 + 3) * 16 + g * 4 + r] = s2B[r];
            }
        }
    }
    __syncthreads();
    if (tid < (two ? 64 : 32)) {
        const int st = tid >> 4, oc = tid & 15;
        const float v = red[(0 * 4 + st) * 16 + oc] + red[(1 * 4 + st) * 16 + oc] +
                        red[(2 * 4 + st) * 16 + oc] + red[(3 * 4 + st) * 16 + oc];
        float* dst = (st < 2) ? statsA : statsB;
        atomicAdd(&dst[(st & 1) * 16 + oc], v);
    }
}

// main conv: logical blocks [0,1920) = support (dual conv), [1920,2016) = anchor.
__global__ __launch_bounds__(256, 4)
void conv_main_kernel(const unsigned short* __restrict__ spad, const unsigned short* __restrict__ apad,
                      const unsigned short* __restrict__ fragR, const float* __restrict__ rb,
                      const unsigned short* __restrict__ fragC, const float* __restrict__ cb,
                      unsigned short* __restrict__ srp, unsigned short* __restrict__ sxpe,
                      unsigned short* __restrict__ axp,
                      float* __restrict__ statsSr, float* __restrict__ statsSx,
                      float* __restrict__ statsAx)
{
    __shared__ __align__(16) unsigned short lds[10 * 98 * 16];
    __shared__ float red[4 * 4 * 16];
    const int bid0 = (blockIdx.x & 7) * 252 + (blockIdx.x >> 3);
    const bool two = bid0 < 1920;
    const int bid = two ? bid0 : bid0 - 1920;
    const int img = bid / 12;
    const int r0b = bid - img * 12;
    const unsigned short* in = (two ? spad : apad) + (size_t)img * 9604 * 16;
    unsigned short* outA = (two ? srp : axp) + (size_t)img * 2304 * 16;
    unsigned short* outB = sxpe + (size_t)img * 9216 * 16;
    conv_tile<true>(lds, red, in, fragR, rb, fragC, cb, outA, outB,
                    two ? statsSr : statsAx, statsSx, r0b, two);
}

// projector conv (deep -> pre_j, unpooled); XCD swizzle (96 = 8*12)
__global__ __launch_bounds__(256, 4)
void conv_j_kernel(const unsigned short* __restrict__ deeppad,
                   const unsigned short* __restrict__ fragJ, const float* __restrict__ jb,
                   unsigned short* __restrict__ pre_j, float* __restrict__ statsJ)
{
    __shared__ __align__(16) unsigned short lds[10 * 98 * 16];
    __shared__ float red[4 * 4 * 16];
    const int bid0 = (blockIdx.x & 7) * 12 + (blockIdx.x >> 3);
    const int img = bid0 / 12;
    const int r0b = bid0 - img * 12;
    conv_tile<false>(lds, red, deeppad + (size_t)img * 9604 * 16, fragJ, jb, nullptr, nullptr,
                     pre_j + (size_t)img * 9216 * 16, nullptr, statsJ, nullptr, r0b, false);
}

// ---------------- sxsum[b][pix][c] = sum_s relu(bn(sx)), stored BF16;
// 5-way s split (320 threads); blocks 0..9 also zero the deeppad halo ring
__global__ __launch_bounds__(320)
void sxsum_kernel(const unsigned short* __restrict__ sx, const float* __restrict__ statsSx,
                  const float* __restrict__ cgm, const float* __restrict__ cbt,
                  unsigned short* __restrict__ out, unsigned short* __restrict__ deeppad)
{
    __shared__ float scl[16], shf[16];
    __shared__ float part[4][64][17];
    const int tid = threadIdx.x;
    if (blockIdx.x < 10) {
        const int idx = blockIdx.x * 320 + tid;
        if (idx < 8 * 388) {
            const int img = idx / 388;
            const int h = idx - img * 388;
            int pr, pc;
            if (h < 98)       { pr = 0;           pc = h; }
            else if (h < 196) { pr = 97;          pc = h - 98; }
            else if (h < 292) { pr = h - 196 + 1; pc = 0; }
            else              { pr = h - 292 + 1; pc = 97; }
            unsigned short* p = deeppad + ((size_t)img * 9604 + pr * 98 + pc) * 16;
            *(uint4*)p = make_uint4(0, 0, 0, 0);
            *(uint4*)(p + 8) = make_uint4(0, 0, 0, 0);
        }
    }
    if (tid < 16) bn_coef(statsSx, 16, tid, 1.f / 1474560.f, cgm, cbt, scl, shf);
    const int b = blockIdx.x / 144;
    const int chunk = blockIdx.x - b * 144;
    const int px = tid & 63, sg = tid >> 6;   // sg 0..4
    const int pix = chunk * 64 + px;
    __syncthreads();
    float acc[16];
    #pragma unroll
    for (int c = 0; c < 16; ++c) acc[c] = 0.f;
    const unsigned short* p = sx + ((size_t)(b * 20 + sg * 4) * 9216 + pix) * 16;
    #pragma unroll
    for (int s = 0; s < 4; ++s) {
        float v[16];
        unpack8(*(const uint4*)p, v);
        unpack8(*(const uint4*)(p + 8), v + 8);
        #pragma unroll
        for (int c = 0; c < 16; ++c) acc[c] += fmaxf(v[c] * scl[c] + shf[c], 0.f);
        p += 9216 * 16;
    }
    if (sg > 0) {
        #pragma unroll
        for (int c = 0; c < 16; ++c) part[sg - 1][px][c] = acc[c];
    }
    __syncthreads();
    if (sg == 0) {
        #pragma unroll
        for (int c = 0; c < 16; ++c)
            acc[c] += (part[0][px][c] + part[1][px][c]) + (part[2][px][c] + part[3][px][c]);
        unsigned short* o = out + ((size_t)b * 9216 + pix) * 16;
        *(uint4*)o = pack8(acc);
        *(uint4*)(o + 8) = pack8(acc + 8);
    }
}

// =====================================================================
// pe = 1x1 conv [support; loo] via ONE mfma per 16 pixels + fused per-(s,c)
// stats. 256 px per block (5760 blocks); sxsum read as bf16.
// =====================================================================
__global__ __launch_bounds__(256)
void pe_kernel(const unsigned short* __restrict__ spad, unsigned short* __restrict__ sxpe,
               const unsigned short* __restrict__ sxsum, const float* __restrict__ statsSx,
               const float* __restrict__ cgm, const float* __restrict__ cbt,
               const float* __restrict__ pw, const float* __restrict__ pb,
               float* __restrict__ statsPe)
{
    __shared__ float sscl[16], sshf[16];
    __shared__ float red[4][2][16];
    const int tid = threadIdx.x;
    if (tid < 16) bn_coef(statsSx, 16, tid, 1.f / 1474560.f, cgm, cbt, sscl, sshf);
    const int lane = tid & 63, wv = tid >> 6;
    const int p = lane & 15, g = lane >> 4;
    const int img = blockIdx.x / 36;
    const int chunk = blockIdx.x - img * 36;
    const int b = img / 20, s = img - b * 20;
    const int c0 = (g & 1) * 8;

    short8 fw;
    {
        const float4 wa = *(const float4*)(pw + p * 32 + g * 8);
        const float4 wb = *(const float4*)(pw + p * 32 + g * 8 + 4);
        fw[0] = (short)f2bf(wa.x); fw[1] = (short)f2bf(wa.y);
        fw[2] = (short)f2bf(wa.z); fw[3] = (short)f2bf(wa.w);
        fw[4] = (short)f2bf(wb.x); fw[5] = (short)f2bf(wb.y);
        fw[6] = (short)f2bf(wb.z); fw[7] = (short)f2bf(wb.w);
    }
    const float4 b4 = *(const float4*)(pb + 4 * g);
    const float bias[4] = {b4.x, b4.y, b4.z, b4.w};
    __syncthreads();
    float scl[8], shf[8];
    #pragma unroll
    for (int e = 0; e < 8; ++e) { scl[e] = sscl[c0 + e]; shf[e] = sshf[c0 + e]; }

    const unsigned short* imgspad = spad + (size_t)img * 9604 * 16;
    unsigned short* imgsx = sxpe + (size_t)img * 9216 * 16;
    const unsigned short* bsum = sxsum + (size_t)b * 9216 * 16;

    float s1[4] = {0.f, 0.f, 0.f, 0.f}, s2[4] = {0.f, 0.f, 0.f, 0.f};

    #pragma unroll
    for (int it = 0; it < 4; ++it) {
        const int pix = chunk * 256 + it * 64 + wv * 16 + p;
        short8 bf;
        if (g < 2) {
            const int row = pix / 96, col = pix - row * 96;
            const int sw = ((col + 1) >> 2) & 1;
            bf = *(const short8*)(imgspad + ((row + 1) * 98 + col + 1) * 16 + (((g ^ sw) & 1) << 3));
        } else {
            float xv[8], smv[8];
            unpack8(*(const uint4*)(imgsx + (size_t)pix * 16 + c0), xv);
            unpack8(*(const uint4*)(bsum + (size_t)pix * 16 + c0), smv);
            #pragma unroll
            for (int e = 0; e < 8; ++e) {
                const float loo = smv[e] - fmaxf(xv[e] * scl[e] + shf[e], 0.f);
                bf[e] = (short)f2bf(loo);
            }
        }
        floatx4 acc = {0.f, 0.f, 0.f, 0.f};
        acc = __builtin_amdgcn_mfma_f32_16x16x32_bf16(fw, bf, acc, 0, 0, 0);
        const float v0 = acc[0] + bias[0], v1 = acc[1] + bias[1];
        const float v2 = acc[2] + bias[2], v3 = acc[3] + bias[3];
        s1[0] += v0; s1[1] += v1; s1[2] += v2; s1[3] += v3;
        s2[0] += v0 * v0; s2[1] += v1 * v1; s2[2] += v2 * v2; s2[3] += v3 * v3;
        *(uint2*)(imgsx + (size_t)pix * 16 + 4 * g) =
            make_uint2((unsigned)f2bf(v0) | ((unsigned)f2bf(v1) << 16),
                       (unsigned)f2bf(v2) | ((unsigned)f2bf(v3) << 16));
    }

    #pragma unroll
    for (int r = 0; r < 4; ++r) {
        #pragma unroll
        for (int d = 1; d < 16; d <<= 1) {
            s1[r] += __shfl_xor(s1[r], d);
            s2[r] += __shfl_xor(s2[r], d);
        }
    }
    if (p == 0) {
        #pragma unroll
        for (int r = 0; r < 4; ++r) { red[wv][0][g * 4 + r] = s1[r]; red[wv][1][g * 4 + r] = s2[r]; }
    }
    __syncthreads();
    if (tid < 32) {
        const int st = tid >> 4, c = tid & 15;
        const float v = red[0][st][c] + red[1][st][c] + red[2][st][c] + red[3][st][c];
        atomicAdd(&statsPe[st * 320 + s * 16 + c], v);
    }
}

// ---------------- deep: mean_s relu(bn_{s,c}(pe)), 5-way s split (320 thr)
__global__ __launch_bounds__(320)
void deep_kernel(const unsigned short* __restrict__ pe, const float* __restrict__ statsPe,
                 const float* __restrict__ pg, const float* __restrict__ pbt,
                 unsigned short* __restrict__ deeppad)
{
    __shared__ float scl[320], shf[320];
    __shared__ float part[4][64][17];
    const int tid = threadIdx.x;
    bn_coef(statsPe, 320, tid, 1.f / 73728.f, pg, pbt, scl, shf);   // 320 threads = 320 coefs
    const int b = blockIdx.x / 144;
    const int chunk = blockIdx.x - b * 144;
    const int px = tid & 63, sg = tid >> 6;   // sg 0..4
    const int pix = chunk * 64 + px;
    __syncthreads();
    float acc[16];
    #pragma unroll
    for (int c = 0; c < 16; ++c) acc[c] = 0.f;
    const unsigned short* p = pe + ((size_t)(b * 20 + sg * 4) * 9216 + pix) * 16;
    #pragma unroll
    for (int s = 0; s < 4; ++s) {
        const int si = sg * 4 + s;
        float v[16];
        unpack8(*(const uint4*)p, v);
        unpack8(*(const uint4*)(p + 8), v + 8);
        #pragma unroll
        for (int c = 0; c < 16; ++c) acc[c] += fmaxf(v[c] * scl[si * 16 + c] + shf[si * 16 + c], 0.f);
        p += 9216 * 16;
    }
    if (sg > 0) {
        #pragma unroll
        for (int c = 0; c < 16; ++c) part[sg - 1][px][c] = acc[c];
    }
    __syncthreads();
    if (sg == 0) {
        #pragma unroll
        for (int c = 0; c < 16; ++c)
            acc[c] = (acc[c] + (part[0][px][c] + part[1][px][c]) + (part[2][px][c] + part[3][px][c])) * 0.05f;
        const int row = pix / 96, col = pix - row * 96;
        const int sw = ((col + 1) >> 2) & 1;
        unsigned short* d = deeppad + ((size_t)b * 9604 + (row + 1) * 98 + col + 1) * 16;
        *(uint4*)(d + (sw << 3)) = pack8(acc);
        *(uint4*)(d + ((sw ^ 1) << 3)) = pack8(acc + 8);
    }
}

// ---------------- proj = maxpool2(softmax_ch(bn(conv_j))), coef prologue
__global__ __launch_bounds__(256)
void proj_kernel(const unsigned short* __restrict__ pj, const float* __restrict__ statsJ,
                 const float* __restrict__ jg, const float* __restrict__ jbt,
                 float* __restrict__ proj)
{
    __shared__ float scl[16], shf[16];
    const int tid = threadIdx.x;
    if (tid < 16) bn_coef(statsJ, 16, tid, 1.f / 73728.f, jg, jbt, scl, shf);
    const int b = blockIdx.x / 9;
    const int opix = (blockIdx.x - b * 9) * 256 + tid;
    __syncthreads();
    const int oi = opix / 48, oj = opix - oi * 48;
    float mx[16];
    #pragma unroll
    for (int c = 0; c < 16; ++c) mx[c] = 0.f;
    #pragma unroll
    for (int dy = 0; dy < 2; ++dy) {
        const unsigned short* q = pj + ((size_t)b * 9216 + (2 * oi + dy) * 96 + 2 * oj) * 16;
        #pragma unroll
        for (int dx = 0; dx < 2; ++dx) {
            float v[16]; float mval = -1e30f;
            unpack8(*(const uint4*)(q + dx * 16), v);
            unpack8(*(const uint4*)(q + dx * 16 + 8), v + 8);
            #pragma unroll
            for (int c = 0; c < 16; ++c) { v[c] = v[c] * scl[c] + shf[c]; mval = fmaxf(mval, v[c]); }
            float ssum = 0.f;
            #pragma unroll
            for (int c = 0; c < 16; ++c) { v[c] = __expf(v[c] - mval); ssum += v[c]; }
            const float inv = 1.f / ssum;
            #pragma unroll
            for (int c = 0; c < 16; ++c) mx[c] = fmaxf(mx[c], v[c] * inv);
        }
    }
    float* o = proj + ((size_t)b * 2304 + opix) * 16;
    #pragma unroll
    for (int q2 = 0; q2 < 4; ++q2)
        *(float4*)(o + 4 * q2) = make_float4(mx[4 * q2], mx[4 * q2 + 1], mx[4 * q2 + 2], mx[4 * q2 + 3]);
}

// ---------------- merged outputs: blocks [0,1440) support, [1440,1512) anchor
__global__ __launch_bounds__(256)
void out_kernel(const unsigned short* __restrict__ srp, const unsigned short* __restrict__ axp,
                const float* __restrict__ statsSr, const float* __restrict__ statsAx,
                const float* __restrict__ rg, const float* __restrict__ rbt,
                const float* __restrict__ proj, float* __restrict__ outS,
                float* __restrict__ outA)
{
    __shared__ float scl[16], shf[16];
    const int tid = threadIdx.x;
    const bool sup = blockIdx.x < 1440;
    if (tid < 16) {
        if (sup) bn_coef(statsSr, 16, tid, 1.f / 1474560.f, rg, rbt, scl, shf);
        else     bn_coef(statsAx, 16, tid, 1.f / 73728.f, rg, rbt, scl, shf);
    }
    const int bid = sup ? blockIdx.x : blockIdx.x - 1440;
    const int bs = bid / 9;
    const int opix = (bid - bs * 9) * 256 + tid;
    const int b = sup ? bs / 20 : bs;
    __syncthreads();
    const unsigned short* p = (sup ? srp : axp) + ((size_t)bs * 2304 + opix) * 16;
    float v[16];
    unpack8(*(const uint4*)p, v);
    unpack8(*(const uint4*)(p + 8), v + 8);
    const float* pr = proj + ((size_t)b * 2304 + opix) * 16;
    float* o = sup ? outS : outA;
    #pragma unroll
    for (int c = 0; c < 16; ++c)
        o[((size_t)bs * 16 + c) * 2304 + opix] = fmaxf(v[c] * scl[c] + shf[c], 0.f) * pr[c];
}

extern "C" void kernel_launch(void* const* d_in, const int* in_sizes, int n_in,
                              void* d_out, int out_size, void* d_ws, size_t ws_size,
                              hipStream_t stream)
{
    const float* anchor  = (const float*)d_in[0];
    const float* support = (const float*)d_in[1];
    const float* cw  = (const float*)d_in[2];
    const float* cb  = (const float*)d_in[3];
    const float* cgm = (const float*)d_in[4];
    const float* cbt = (const float*)d_in[5];
    const float* pw  = (const float*)d_in[6];
    const float* pb  = (const float*)d_in[7];
    const float* pg  = (const float*)d_in[8];
    const float* pbt = (const float*)d_in[9];
    const float* jw  = (const float*)d_in[10];
    const float* jb  = (const float*)d_in[11];
    const float* jg  = (const float*)d_in[12];
    const float* jbt = (const float*)d_in[13];
    const float* rw  = (const float*)d_in[14];
    const float* rb  = (const float*)d_in[15];
    const float* rg  = (const float*)d_in[16];
    const float* rbt = (const float*)d_in[17];
    float* out = (float*)d_out;

    char* ws = (char*)d_ws;
    // spad [0, 49.2MB) dead after pe -> pre_j/proj overlay it.
    // apad [49.2MB, 51.6MB) dead after conv_main -> deeppad overlays it.
    unsigned short* spad    = (unsigned short*)ws;
    unsigned short* pre_j   = (unsigned short*)(ws + 2458624);           // overlay (post-pe)
    float*          proj    = (float*)(ws + 4817920);                    // overlay (post-pe)
    unsigned short* apad    = (unsigned short*)(ws + 49172480);          // 2,458,624
    unsigned short* deeppad = apad;                                      // overlay (post conv_main)
    unsigned short* sxpe    = (unsigned short*)(ws + 51631104);          // 47,185,920
    unsigned short* srp     = (unsigned short*)(ws + 98817024);          // 11,796,480
    unsigned short* axp     = (unsigned short*)(ws + 110613504);         // 589,824
    unsigned short* sxsum   = (unsigned short*)(ws + 111203328);         // 2,359,296 (bf16)
    unsigned short* frag    = (unsigned short*)(ws + 115921920);         // 15,360
    float*          stats   = (float*)(ws + 115937280);                  // 3,072

    unsigned short* fragR = frag;
    unsigned short* fragC = frag + 5 * 64 * 8;
    unsigned short* fragJ = frag + 10 * 64 * 8;
    float* statsAx = stats,      *statsSr = stats + 32, *statsSx = stats + 64;
    float* statsPe = stats + 96, *statsJ  = stats + 736;

    pack_kernel<<<6308, 256, 0, stream>>>(support, anchor, spad, apad, rw, cw, jw, frag, stats);
    conv_main_kernel<<<2016, 256, 0, stream>>>(spad, apad, fragR, rb, fragC, cb,
                                               srp, sxpe, axp, statsSr, statsSx, statsAx);
    // apad dead from here: deeppad overlays it (halo zeroed inside sxsum)
    sxsum_kernel<<<1152, 320, 0, stream>>>(sxpe, statsSx, cgm, cbt, sxsum, deeppad);
    pe_kernel<<<5760, 256, 0, stream>>>(spad, sxpe, sxsum, statsSx, cgm, cbt, pw, pb, statsPe);
    // spad dead from here: pre_j / proj overlay it
    deep_kernel<<<1152, 320, 0, stream>>>(sxpe, statsPe, pg, pbt, deeppad);
    conv_j_kernel<<<96, 256, 0, stream>>>(deeppad, fragJ, jb, pre_j, statsJ);
    proj_kernel<<<72, 256, 0, stream>>>(pre_j, statsJ, jg, jbt, proj);
    out_kernel<<<1512, 256, 0, stream>>>(srp, axp, statsSr, statsAx, rg, rbt, proj,
                                         out + 294912, out);
}